// Round 5
// baseline (1637.931 us; speedup 1.0000x reference)
//
#include <hip/hip_runtime.h>
#include <cstddef>
#include <cmath>

#define BATCH 2
#define LSEQ 2048
#define DM 1024
#define DSTATE 16
#define DI 2048
#define DTR 64
#define XDR 96   // DTR + 2*DSTATE

using f32x4 = __attribute__((ext_vector_type(4))) float;
using bf16x8 = __attribute__((ext_vector_type(8))) short;

__device__ __forceinline__ unsigned short f2bf(float f) {
  union { float f; unsigned int u; } c; c.f = f;
  unsigned int u = c.u;
  return (unsigned short)((u + 0x7FFFu + ((u >> 16) & 1u)) >> 16);  // RNE
}
__device__ __forceinline__ unsigned int pack2(float a, float b) {
  return (unsigned int)f2bf(a) | ((unsigned int)f2bf(b) << 16);
}

// ---------------------------------------------------------------------------
// NT GEMM via bf16 MFMA: C[m,n] = sum_k A[m*lda+k] * B[n*ldb+k], f32 in/out.
// BM=BN=128, BK=32, 256 threads = 4 waves (2x2), 64x64 per wave.
// Requires M%128==0, N%128==0, K%32==0 (true for all call sites).
// LDS rows padded to 40 shorts (80B stride): ds_read_b128 conflicts <=2-way.
// ---------------------------------------------------------------------------
__global__ __launch_bounds__(256) void gemm_nt_mfma(
    const float* __restrict__ A, const float* __restrict__ B,
    float* __restrict__ C, int K, int lda, int ldb, int ldc) {
  __shared__ __align__(16) unsigned short As[128][40];
  __shared__ __align__(16) unsigned short Bs[128][40];

  const int tid = threadIdx.x;
  const int lane = tid & 63;
  const int wid = tid >> 6;
  const int wm = (wid >> 1) * 64;  // wave row offset in tile
  const int wn = (wid & 1) * 64;   // wave col offset in tile
  const size_t m0 = (size_t)blockIdx.y * 128;
  const size_t n0 = (size_t)blockIdx.x * 128;

  // staging: thread t loads 16 consecutive floats of one row (A and B tiles)
  const int srow = tid >> 1;
  const int skb = (tid & 1) * 16;
  const float* ag = &A[(m0 + srow) * lda + skb];
  const float* bg = &B[(n0 + srow) * ldb + skb];
  uint4* adst = reinterpret_cast<uint4*>(&As[srow][skb]);  // 16B-aligned
  uint4* bdst = reinterpret_cast<uint4*>(&Bs[srow][skb]);

  f32x4 acc[4][4] = {};

  const int fr = lane & 15;         // row (A) / col (B) within 16x16 fragment
  const int fko = (lane >> 4) * 8;  // k offset in elements

  for (int k0 = 0; k0 < K; k0 += 32) {
    const float4* ap = reinterpret_cast<const float4*>(ag + k0);
    const float4* bp = reinterpret_cast<const float4*>(bg + k0);
    float4 a0 = ap[0], a1 = ap[1], a2 = ap[2], a3 = ap[3];
    float4 b0 = bp[0], b1 = bp[1], b2 = bp[2], b3 = bp[3];

    adst[0] = make_uint4(pack2(a0.x, a0.y), pack2(a0.z, a0.w),
                         pack2(a1.x, a1.y), pack2(a1.z, a1.w));
    adst[1] = make_uint4(pack2(a2.x, a2.y), pack2(a2.z, a2.w),
                         pack2(a3.x, a3.y), pack2(a3.z, a3.w));
    bdst[0] = make_uint4(pack2(b0.x, b0.y), pack2(b0.z, b0.w),
                         pack2(b1.x, b1.y), pack2(b1.z, b1.w));
    bdst[1] = make_uint4(pack2(b2.x, b2.y), pack2(b2.z, b2.w),
                         pack2(b3.x, b3.y), pack2(b3.z, b3.w));
    __syncthreads();

    bf16x8 af[4], bfr[4];
#pragma unroll
    for (int i = 0; i < 4; ++i) {
      af[i] = *reinterpret_cast<const bf16x8*>(&As[wm + i * 16 + fr][fko]);
      bfr[i] = *reinterpret_cast<const bf16x8*>(&Bs[wn + i * 16 + fr][fko]);
    }
#pragma unroll
    for (int i = 0; i < 4; ++i)
#pragma unroll
      for (int j = 0; j < 4; ++j)
        acc[i][j] = __builtin_amdgcn_mfma_f32_16x16x32_bf16(
            af[i], bfr[j], acc[i][j], 0, 0, 0);
    __syncthreads();
  }

  // C/D layout: col = lane&15, row = (lane>>4)*4 + reg  [m89/m91]
  const int crb = (lane >> 4) * 4;
#pragma unroll
  for (int i = 0; i < 4; ++i) {
    size_t row = m0 + wm + i * 16 + crb;
#pragma unroll
    for (int j = 0; j < 4; ++j) {
      size_t col = n0 + wn + j * 16 + fr;
#pragma unroll
      for (int r = 0; r < 4; ++r)
        C[(row + r) * ldc + col] = acc[i][j][r];
    }
  }
}

// ---------------------------------------------------------------------------
// Tiled f32 GEMM, NT layout, with optional split-K along blockIdx.z:
// chunk z computes sum over k in [z*K, (z+1)*K) and writes C + z*M*ldc.
// ---------------------------------------------------------------------------
template<int BM, int BN, int BK, int TM, int TN>
__global__ __launch_bounds__(256) void gemm_nt(
    const float* __restrict__ A, const float* __restrict__ B,
    float* __restrict__ C,
    int M, int N, int K, int lda, int ldb, int ldc) {
  constexpr int THREADS = (BM / TM) * (BN / TN);
  static_assert(THREADS == 256, "block must be 256");
  constexpr int PAD = 4;
  __shared__ float As[BK][BM + PAD];
  __shared__ float Bs[BK][BN + PAD];

  A += (size_t)blockIdx.z * K;
  B += (size_t)blockIdx.z * K;
  C += (size_t)blockIdx.z * (size_t)M * ldc;

  const int tid = threadIdx.x;
  const int tc = tid % (BN / TN);
  const int tr = tid / (BN / TN);
  const int m0 = blockIdx.y * BM;
  const int n0 = blockIdx.x * BN;

  float acc[TM][TN];
#pragma unroll
  for (int i = 0; i < TM; ++i)
#pragma unroll
    for (int j = 0; j < TN; ++j) acc[i][j] = 0.f;

  constexpr int AV = BM * BK / 4 / THREADS;
  constexpr int BV = BN * BK / 4 / THREADS;

  for (int k0 = 0; k0 < K; k0 += BK) {
#pragma unroll
    for (int i = 0; i < AV; ++i) {
      int f = tid + i * THREADS;
      int r = f / (BK / 4);
      int c4 = (f % (BK / 4)) * 4;
      int gm = m0 + r, gk = k0 + c4;
      float4 v = make_float4(0.f, 0.f, 0.f, 0.f);
      if (gm < M && gk < K)
        v = *reinterpret_cast<const float4*>(&A[(size_t)gm * lda + gk]);
      As[c4 + 0][r] = v.x;
      As[c4 + 1][r] = v.y;
      As[c4 + 2][r] = v.z;
      As[c4 + 3][r] = v.w;
    }
#pragma unroll
    for (int i = 0; i < BV; ++i) {
      int f = tid + i * THREADS;
      int r = f / (BK / 4);
      int c4 = (f % (BK / 4)) * 4;
      int gn = n0 + r, gk = k0 + c4;
      float4 v = make_float4(0.f, 0.f, 0.f, 0.f);
      if (gn < N && gk < K)
        v = *reinterpret_cast<const float4*>(&B[(size_t)gn * ldb + gk]);
      Bs[c4 + 0][r] = v.x;
      Bs[c4 + 1][r] = v.y;
      Bs[c4 + 2][r] = v.z;
      Bs[c4 + 3][r] = v.w;
    }
    __syncthreads();

#pragma unroll
    for (int k = 0; k < BK; ++k) {
      float a[TM], bb[TN];
#pragma unroll
      for (int h = 0; h < TM; h += 4)
        *reinterpret_cast<float4*>(&a[h]) =
            *reinterpret_cast<const float4*>(&As[k][tr * TM + h]);
#pragma unroll
      for (int h = 0; h < TN; h += 4)
        *reinterpret_cast<float4*>(&bb[h]) =
            *reinterpret_cast<const float4*>(&Bs[k][tc * TN + h]);
#pragma unroll
      for (int i = 0; i < TM; ++i)
#pragma unroll
        for (int j = 0; j < TN; ++j) acc[i][j] = fmaf(a[i], bb[j], acc[i][j]);
    }
    __syncthreads();
  }

#pragma unroll
  for (int i = 0; i < TM; ++i) {
    int gm = m0 + tr * TM + i;
    if (gm >= M) continue;
#pragma unroll
    for (int j4 = 0; j4 < TN; j4 += 4) {
      int gn = n0 + tc * TN + j4;
      if (gn + 3 < N) {
        float4 v = make_float4(acc[i][j4], acc[i][j4 + 1], acc[i][j4 + 2],
                               acc[i][j4 + 3]);
        *reinterpret_cast<float4*>(&C[(size_t)gm * ldc + gn]) = v;
      } else {
#pragma unroll
        for (int j = 0; j < 4; ++j)
          if (gn + j < N) C[(size_t)gm * ldc + gn + j] = acc[i][j4 + j];
      }
    }
  }
}

// 4-way split-K reduction: o[i] = sum_z P[z*n + i]
__global__ __launch_bounds__(256) void reduce4_kernel(
    const float* __restrict__ P, float* __restrict__ o, int n) {
  int i = blockIdx.x * 256 + threadIdx.x;
  if (i < n) o[i] = (P[i] + P[n + i]) + (P[2 * n + i] + P[3 * n + i]);
}

// ---------------------------------------------------------------------------
// Depthwise causal conv (D_CONV=4) + bias + SiLU.  x layout (B, L, E).
// ---------------------------------------------------------------------------
__global__ __launch_bounds__(256) void conv_silu_kernel(
    const float* __restrict__ x, const float* __restrict__ w,
    const float* __restrict__ cb, float* __restrict__ out) {
  int idx = blockIdx.x * 256 + threadIdx.x;
  int e4 = idx % (DI / 4);
  int bl = idx / (DI / 4);
  int l = bl % LSEQ;
  int e = e4 * 4;

  const float4* cw = reinterpret_cast<const float4*>(w);
  float4 w0 = cw[e], w1 = cw[e + 1], w2 = cw[e + 2], w3 = cw[e + 3];
  float4 acc = *reinterpret_cast<const float4*>(&cb[e]);

#define TAPK(K, COMP)                                                       \
  {                                                                         \
    int ls = l - 3 + (K);                                                   \
    if (ls >= 0) {                                                          \
      float4 xv = *reinterpret_cast<const float4*>(                         \
          &x[((size_t)(bl) - 3 + (K)) * DI + e]);                           \
      acc.x = fmaf(xv.x, w0.COMP, acc.x);                                   \
      acc.y = fmaf(xv.y, w1.COMP, acc.y);                                   \
      acc.z = fmaf(xv.z, w2.COMP, acc.z);                                   \
      acc.w = fmaf(xv.w, w3.COMP, acc.w);                                   \
    }                                                                       \
  }
  TAPK(0, x)
  TAPK(1, y)
  TAPK(2, z)
  TAPK(3, w)
#undef TAPK

  acc.x = acc.x / (1.f + expf(-acc.x));
  acc.y = acc.y / (1.f + expf(-acc.y));
  acc.z = acc.z / (1.f + expf(-acc.z));
  acc.w = acc.w / (1.f + expf(-acc.w));
  *reinterpret_cast<float4*>(&out[(size_t)bl * DI + e]) = acc;
}

// ---------------------------------------------------------------------------
// Selective scan.  Thread = (b, e, n); 16 lanes (n) per channel, shuffle-
// reduce for y.  Reads delta_raw from dg and writes gated output g in-place.
// ---------------------------------------------------------------------------
__global__ __launch_bounds__(256) void scan_kernel(
    float* dg, const float* __restrict__ u, const float* __restrict__ z,
    const float* __restrict__ xdbl, const float* __restrict__ dtb,
    const float* __restrict__ A_log, const float* __restrict__ Dv) {
  int tid = blockIdx.x * 256 + threadIdx.x;
  int n = tid & 15;
  int e = (tid >> 4) & (DI - 1);
  int b = tid >> 15;

  float nA = -expf(A_log[e * DSTATE + n]);
  float bias = dtb[e];
  float Dval = Dv[e];

  size_t base = ((size_t)b * LSEQ) * DI + e;
  size_t xb = (size_t)b * LSEQ * XDR;

  float s = 0.f;
  float draw = dg[base];
  float ut = u[base];
  float zt = z[base];
  float Bt = xdbl[xb + 64 + n];
  float Ct = xdbl[xb + 80 + n];

  for (int t = 0; t < LSEQ; ++t) {
    float draw_n = 0.f, ut_n = 0.f, zt_n = 0.f, Bt_n = 0.f, Ct_n = 0.f;
    if (t + 1 < LSEQ) {
      size_t idx = base + (size_t)(t + 1) * DI;
      draw_n = dg[idx];
      ut_n = u[idx];
      zt_n = z[idx];
      Bt_n = xdbl[xb + (size_t)(t + 1) * XDR + 64 + n];
      Ct_n = xdbl[xb + (size_t)(t + 1) * XDR + 80 + n];
    }

    float xx = draw + bias;
    float d = (xx > 20.f) ? xx : log1pf(expf(xx));
    float dA = expf(d * nA);
    s = fmaf(s, dA, d * ut * Bt);
    float yy = s * Ct;
    yy += __shfl_xor(yy, 1);
    yy += __shfl_xor(yy, 2);
    yy += __shfl_xor(yy, 4);
    yy += __shfl_xor(yy, 8);
    if (n == 0) {
      float gate = zt / (1.f + expf(-zt));
      dg[base + (size_t)t * DI] = (yy + Dval * ut) * gate;
    }

    draw = draw_n;
    ut = ut_n;
    zt = zt_n;
    Bt = Bt_n;
    Ct = Ct_n;
  }
}

// ---------------------------------------------------------------------------
extern "C" void kernel_launch(void* const* d_in, const int* in_sizes, int n_in,
                              void* d_out, int out_size, void* d_ws,
                              size_t ws_size, hipStream_t stream) {
  const float* hs = (const float*)d_in[0];
  const float* in2 = (const float*)d_in[1];
  const float* w1 = (const float*)d_in[2];
  const float* w2 = (const float*)d_in[3];
  const float* cw = (const float*)d_in[4];
  const float* cb = (const float*)d_in[5];
  const float* xpw = (const float*)d_in[6];
  const float* dtw = (const float*)d_in[7];
  const float* dtb = (const float*)d_in[8];
  const float* alog = (const float*)d_in[9];
  const float* Dv = (const float*)d_in[10];
  const float* ow = (const float*)d_in[11];
  float* out = (float*)d_out;

  const size_t BLE = (size_t)BATCH * LSEQ * DI;
  const size_t XDN = (size_t)BATCH * LSEQ * XDR;  // 393216
  float* bufX = (float*)d_ws;       // x_pre -> delta_raw -> g (reused)
  float* bufZ = bufX + BLE;         // z
  float* bufU = bufZ + BLE;         // u
  float* bufXD = bufU + BLE;        // x_dbl (B,L,96)
  float* bufP = bufXD + XDN;        // split-K partials: 4 x (M x 96)

  const int M = BATCH * LSEQ;  // 4096
  dim3 blk(256);

  // 1. x_pre = hs @ w1^T   (MFMA bf16)
  gemm_nt_mfma<<<dim3(DI / 128, M / 128), blk, 0, stream>>>(
      hs, w1, bufX, DM, DM, DM, DI);
  // 2. z = in2 @ w2^T      (MFMA bf16)
  gemm_nt_mfma<<<dim3(DI / 128, M / 128), blk, 0, stream>>>(
      in2, w2, bufZ, DM, DM, DM, DI);
  // 3. u = silu(conv(x_pre) + cb)
  conv_silu_kernel<<<(M * (DI / 4)) / 256, blk, 0, stream>>>(bufX, cw, cb,
                                                             bufU);
  // 4. x_dbl partials = u @ xpw^T, split-K x4  (f32)
  gemm_nt<128, 128, 16, 8, 8><<<dim3(1, M / 128, 4), blk, 0, stream>>>(
      bufU, xpw, bufP, M, XDR, DI / 4, DI, DI, XDR);
  // 4b. reduce partials -> bufXD
  reduce4_kernel<<<(int)((XDN + 255) / 256), blk, 0, stream>>>(bufP, bufXD,
                                                               (int)XDN);
  // 5. delta_raw = dt @ dtw^T  (f32, K=64)
  gemm_nt<128, 128, 16, 8, 8><<<dim3(DI / 128, M / 128), blk, 0, stream>>>(
      bufXD, dtw, bufX, M, DI, DTR, XDR, DTR, DI);
  // 6. scan (in-place: bufX delta_raw -> g)
  scan_kernel<<<(BATCH * DI * DSTATE) / 256, blk, 0, stream>>>(
      bufX, bufU, bufZ, bufXD, dtb, alog, Dv);
  // 7. out = g @ ow^T      (MFMA bf16)
  gemm_nt_mfma<<<dim3(DM / 128, M / 128), blk, 0, stream>>>(
      bufX, ow, out, DI, DI, DI, DM);
}

// Round 7
// 690.833 us; speedup vs baseline: 2.3710x; 2.3710x over previous
//
#include <hip/hip_runtime.h>
#include <cstddef>
#include <cmath>

#define BATCH 2
#define LSEQ 2048
#define DM 1024
#define DSTATE 16
#define DI 2048
#define DTR 64
#define XDR 96   // DTR + 2*DSTATE
#define NC 32    // scan chunks
#define TC 64    // timesteps per chunk (NC*TC == LSEQ)

using f32x4 = __attribute__((ext_vector_type(4))) float;
using bf16x8 = __attribute__((ext_vector_type(8))) short;

__device__ __forceinline__ unsigned short f2bf(float f) {
  union { float f; unsigned int u; } c; c.f = f;
  unsigned int u = c.u;
  return (unsigned short)((u + 0x7FFFu + ((u >> 16) & 1u)) >> 16);  // RNE
}
__device__ __forceinline__ unsigned int pack2(float a, float b) {
  return (unsigned int)f2bf(a) | ((unsigned int)f2bf(b) << 16);
}

// ---------------------------------------------------------------------------
// NT GEMM via bf16 MFMA: C[m,n] = sum_k A[m*lda+k] * B[n*ldb+k], f32 in/out.
// BM=BN=128, BK=32, 256 threads = 4 waves (2x2), 64x64 per wave.
// Requires M%128==0, N%128==0, K%32==0 (true for all call sites).
// ---------------------------------------------------------------------------
__global__ __launch_bounds__(256) void gemm_nt_mfma(
    const float* __restrict__ A, const float* __restrict__ B,
    float* __restrict__ C, int K, int lda, int ldb, int ldc) {
  __shared__ __align__(16) unsigned short As[128][40];
  __shared__ __align__(16) unsigned short Bs[128][40];

  const int tid = threadIdx.x;
  const int lane = tid & 63;
  const int wid = tid >> 6;
  const int wm = (wid >> 1) * 64;
  const int wn = (wid & 1) * 64;
  const size_t m0 = (size_t)blockIdx.y * 128;
  const size_t n0 = (size_t)blockIdx.x * 128;

  const int srow = tid >> 1;
  const int skb = (tid & 1) * 16;
  const float* ag = &A[(m0 + srow) * lda + skb];
  const float* bg = &B[(n0 + srow) * ldb + skb];
  uint4* adst = reinterpret_cast<uint4*>(&As[srow][skb]);
  uint4* bdst = reinterpret_cast<uint4*>(&Bs[srow][skb]);

  f32x4 acc[4][4] = {};

  const int fr = lane & 15;
  const int fko = (lane >> 4) * 8;

  for (int k0 = 0; k0 < K; k0 += 32) {
    const float4* ap = reinterpret_cast<const float4*>(ag + k0);
    const float4* bp = reinterpret_cast<const float4*>(bg + k0);
    float4 a0 = ap[0], a1 = ap[1], a2 = ap[2], a3 = ap[3];
    float4 b0 = bp[0], b1 = bp[1], b2 = bp[2], b3 = bp[3];

    adst[0] = make_uint4(pack2(a0.x, a0.y), pack2(a0.z, a0.w),
                         pack2(a1.x, a1.y), pack2(a1.z, a1.w));
    adst[1] = make_uint4(pack2(a2.x, a2.y), pack2(a2.z, a2.w),
                         pack2(a3.x, a3.y), pack2(a3.z, a3.w));
    bdst[0] = make_uint4(pack2(b0.x, b0.y), pack2(b0.z, b0.w),
                         pack2(b1.x, b1.y), pack2(b1.z, b1.w));
    bdst[1] = make_uint4(pack2(b2.x, b2.y), pack2(b2.z, b2.w),
                         pack2(b3.x, b3.y), pack2(b3.z, b3.w));
    __syncthreads();

    bf16x8 af[4], bfr[4];
#pragma unroll
    for (int i = 0; i < 4; ++i) {
      af[i] = *reinterpret_cast<const bf16x8*>(&As[wm + i * 16 + fr][fko]);
      bfr[i] = *reinterpret_cast<const bf16x8*>(&Bs[wn + i * 16 + fr][fko]);
    }
#pragma unroll
    for (int i = 0; i < 4; ++i)
#pragma unroll
      for (int j = 0; j < 4; ++j)
        acc[i][j] = __builtin_amdgcn_mfma_f32_16x16x32_bf16(
            af[i], bfr[j], acc[i][j], 0, 0, 0);
    __syncthreads();
  }

  const int crb = (lane >> 4) * 4;
#pragma unroll
  for (int i = 0; i < 4; ++i) {
    size_t row = m0 + wm + i * 16 + crb;
#pragma unroll
    for (int j = 0; j < 4; ++j) {
      size_t col = n0 + wn + j * 16 + fr;
#pragma unroll
      for (int r = 0; r < 4; ++r)
        C[(row + r) * ldc + col] = acc[i][j][r];
    }
  }
}

// ---------------------------------------------------------------------------
// Tiled f32 GEMM, NT layout, with split-K along blockIdx.z.
// ---------------------------------------------------------------------------
template<int BM, int BN, int BK, int TM, int TN>
__global__ __launch_bounds__(256) void gemm_nt(
    const float* __restrict__ A, const float* __restrict__ B,
    float* __restrict__ C,
    int M, int N, int K, int lda, int ldb, int ldc) {
  constexpr int THREADS = (BM / TM) * (BN / TN);
  static_assert(THREADS == 256, "block must be 256");
  constexpr int PAD = 4;
  __shared__ float As[BK][BM + PAD];
  __shared__ float Bs[BK][BN + PAD];

  A += (size_t)blockIdx.z * K;
  B += (size_t)blockIdx.z * K;
  C += (size_t)blockIdx.z * (size_t)M * ldc;

  const int tid = threadIdx.x;
  const int tc = tid % (BN / TN);
  const int tr = tid / (BN / TN);
  const int m0 = blockIdx.y * BM;
  const int n0 = blockIdx.x * BN;

  float acc[TM][TN];
#pragma unroll
  for (int i = 0; i < TM; ++i)
#pragma unroll
    for (int j = 0; j < TN; ++j) acc[i][j] = 0.f;

  constexpr int AV = BM * BK / 4 / THREADS;
  constexpr int BV = BN * BK / 4 / THREADS;

  for (int k0 = 0; k0 < K; k0 += BK) {
#pragma unroll
    for (int i = 0; i < AV; ++i) {
      int f = tid + i * THREADS;
      int r = f / (BK / 4);
      int c4 = (f % (BK / 4)) * 4;
      int gm = m0 + r, gk = k0 + c4;
      float4 v = make_float4(0.f, 0.f, 0.f, 0.f);
      if (gm < M && gk < K)
        v = *reinterpret_cast<const float4*>(&A[(size_t)gm * lda + gk]);
      As[c4 + 0][r] = v.x;
      As[c4 + 1][r] = v.y;
      As[c4 + 2][r] = v.z;
      As[c4 + 3][r] = v.w;
    }
#pragma unroll
    for (int i = 0; i < BV; ++i) {
      int f = tid + i * THREADS;
      int r = f / (BK / 4);
      int c4 = (f % (BK / 4)) * 4;
      int gn = n0 + r, gk = k0 + c4;
      float4 v = make_float4(0.f, 0.f, 0.f, 0.f);
      if (gn < N && gk < K)
        v = *reinterpret_cast<const float4*>(&B[(size_t)gn * ldb + gk]);
      Bs[c4 + 0][r] = v.x;
      Bs[c4 + 1][r] = v.y;
      Bs[c4 + 2][r] = v.z;
      Bs[c4 + 3][r] = v.w;
    }
    __syncthreads();

#pragma unroll
    for (int k = 0; k < BK; ++k) {
      float a[TM], bb[TN];
#pragma unroll
      for (int h = 0; h < TM; h += 4)
        *reinterpret_cast<float4*>(&a[h]) =
            *reinterpret_cast<const float4*>(&As[k][tr * TM + h]);
#pragma unroll
      for (int h = 0; h < TN; h += 4)
        *reinterpret_cast<float4*>(&bb[h]) =
            *reinterpret_cast<const float4*>(&Bs[k][tc * TN + h]);
#pragma unroll
      for (int i = 0; i < TM; ++i)
#pragma unroll
        for (int j = 0; j < TN; ++j) acc[i][j] = fmaf(a[i], bb[j], acc[i][j]);
    }
    __syncthreads();
  }

#pragma unroll
  for (int i = 0; i < TM; ++i) {
    int gm = m0 + tr * TM + i;
    if (gm >= M) continue;
#pragma unroll
    for (int j4 = 0; j4 < TN; j4 += 4) {
      int gn = n0 + tc * TN + j4;
      if (gn + 3 < N) {
        float4 v = make_float4(acc[i][j4], acc[i][j4 + 1], acc[i][j4 + 2],
                               acc[i][j4 + 3]);
        *reinterpret_cast<float4*>(&C[(size_t)gm * ldc + gn]) = v;
      } else {
#pragma unroll
        for (int j = 0; j < 4; ++j)
          if (gn + j < N) C[(size_t)gm * ldc + gn + j] = acc[i][j4 + j];
      }
    }
  }
}

// 4-way split-K reduction: o[i] = sum_z P[z*n + i]
__global__ __launch_bounds__(256) void reduce4_kernel(
    const float* __restrict__ P, float* __restrict__ o, int n) {
  int i = blockIdx.x * 256 + threadIdx.x;
  if (i < n) o[i] = (P[i] + P[n + i]) + (P[2 * n + i] + P[3 * n + i]);
}

// ---------------------------------------------------------------------------
// Depthwise causal conv (D_CONV=4) + bias + SiLU.  x layout (B, L, E).
// ---------------------------------------------------------------------------
__global__ __launch_bounds__(256) void conv_silu_kernel(
    const float* __restrict__ x, const float* __restrict__ w,
    const float* __restrict__ cb, float* __restrict__ out) {
  int idx = blockIdx.x * 256 + threadIdx.x;
  int e4 = idx % (DI / 4);
  int bl = idx / (DI / 4);
  int l = bl % LSEQ;
  int e = e4 * 4;

  const float4* cw = reinterpret_cast<const float4*>(w);
  float4 w0 = cw[e], w1 = cw[e + 1], w2 = cw[e + 2], w3 = cw[e + 3];
  float4 acc = *reinterpret_cast<const float4*>(&cb[e]);

#define TAPK(K, COMP)                                                       \
  {                                                                         \
    int ls = l - 3 + (K);                                                   \
    if (ls >= 0) {                                                          \
      float4 xv = *reinterpret_cast<const float4*>(                         \
          &x[((size_t)(bl) - 3 + (K)) * DI + e]);                           \
      acc.x = fmaf(xv.x, w0.COMP, acc.x);                                   \
      acc.y = fmaf(xv.y, w1.COMP, acc.y);                                   \
      acc.z = fmaf(xv.z, w2.COMP, acc.z);                                   \
      acc.w = fmaf(xv.w, w3.COMP, acc.w);                                   \
    }                                                                       \
  }
  TAPK(0, x)
  TAPK(1, y)
  TAPK(2, z)
  TAPK(3, w)
#undef TAPK

  acc.x = acc.x / (1.f + expf(-acc.x));
  acc.y = acc.y / (1.f + expf(-acc.y));
  acc.z = acc.z / (1.f + expf(-acc.z));
  acc.w = acc.w / (1.f + expf(-acc.w));
  *reinterpret_cast<float4*>(&out[(size_t)bl * DI + e]) = acc;
}

// ---------------------------------------------------------------------------
// Chunked selective scan.  Recurrence s_t = dA_t*s_{t-1} + dB_t is linear,
// so: pass A computes per-chunk (end-state from 0, decay product); pass B
// scans chunk summaries; pass C replays each chunk seeded with the correct
// initial state and emits gated output.  Identical fast-math formulas in A
// and C keep the recompute consistent.
// ---------------------------------------------------------------------------
__device__ __forceinline__ float softplus_fast(float x) {
  float ex = __expf(x);
  return (x > 20.f) ? x : __logf(1.f + ex);
}

__global__ __launch_bounds__(256) void scan_passA(
    const float* __restrict__ draw, const float* __restrict__ u,
    const float* __restrict__ xdbl, const float* __restrict__ dtb,
    const float* __restrict__ A_log, float* __restrict__ sEnd,
    float* __restrict__ sProd) {
  int g = blockIdx.x * 256 + threadIdx.x;  // 2,097,152 threads
  int n = g & 15;
  int e = (g >> 4) & (DI - 1);
  int c = (g >> 15) & (NC - 1);
  int b = g >> 20;

  float nA = -__expf(A_log[e * DSTATE + n]);
  float bias = dtb[e];
  size_t off = ((size_t)b * LSEQ + c * TC) * DI + e;
  size_t xoff = ((size_t)b * LSEQ + c * TC) * XDR;

  float s = 0.f, P = 1.f;
  for (int t = 0; t < TC; ++t) {
    float dr = draw[off];
    float ut = u[off];
    float Bt = xdbl[xoff + 64 + n];
    float d = softplus_fast(dr + bias);
    float dA = __expf(d * nA);
    s = fmaf(s, dA, d * ut * Bt);
    P *= dA;
    off += DI;
    xoff += XDR;
  }
  size_t o = (((size_t)b * NC + c) * DI + e) * DSTATE + n;
  sEnd[o] = s;
  sProd[o] = P;
}

__global__ __launch_bounds__(256) void scan_passB(
    const float* __restrict__ sEnd, const float* __restrict__ sProd,
    float* __restrict__ sInit) {
  int g = blockIdx.x * 256 + threadIdx.x;  // 65,536 threads
  int n = g & 15;
  int e = (g >> 4) & (DI - 1);
  int b = g >> 15;
  float s = 0.f;
  for (int c = 0; c < NC; ++c) {
    size_t o = (((size_t)b * NC + c) * DI + e) * DSTATE + n;
    sInit[o] = s;
    s = fmaf(s, sProd[o], sEnd[o]);  // s = sEnd[c] + P[c]*s
  }
}

__global__ __launch_bounds__(256) void scan_passC(
    float* dg, const float* __restrict__ u, const float* __restrict__ z,
    const float* __restrict__ xdbl, const float* __restrict__ dtb,
    const float* __restrict__ A_log, const float* __restrict__ Dv,
    const float* __restrict__ sInit) {
  int g = blockIdx.x * 256 + threadIdx.x;  // 2,097,152 threads
  int n = g & 15;
  int e = (g >> 4) & (DI - 1);
  int c = (g >> 15) & (NC - 1);
  int b = g >> 20;

  float nA = -__expf(A_log[e * DSTATE + n]);
  float bias = dtb[e];
  float Dval = Dv[e];
  size_t off = ((size_t)b * LSEQ + c * TC) * DI + e;
  size_t xoff = ((size_t)b * LSEQ + c * TC) * XDR;
  float s = sInit[(((size_t)b * NC + c) * DI + e) * DSTATE + n];

  for (int t = 0; t < TC; ++t) {
    float dr = dg[off];
    float ut = u[off];
    float zt = z[off];
    float Bt = xdbl[xoff + 64 + n];
    float Ct = xdbl[xoff + 80 + n];
    float d = softplus_fast(dr + bias);
    float dA = __expf(d * nA);
    s = fmaf(s, dA, d * ut * Bt);
    float yy = s * Ct;
    yy += __shfl_xor(yy, 1);
    yy += __shfl_xor(yy, 2);
    yy += __shfl_xor(yy, 4);
    yy += __shfl_xor(yy, 8);
    if (n == 0) {
      float gate = zt / (1.f + __expf(-zt));
      dg[off] = (yy + Dval * ut) * gate;  // same 16-lane group read dr above
    }
    off += DI;
    xoff += XDR;
  }
}

// ---------------------------------------------------------------------------
extern "C" void kernel_launch(void* const* d_in, const int* in_sizes, int n_in,
                              void* d_out, int out_size, void* d_ws,
                              size_t ws_size, hipStream_t stream) {
  const float* hs = (const float*)d_in[0];
  const float* in2 = (const float*)d_in[1];
  const float* w1 = (const float*)d_in[2];
  const float* w2 = (const float*)d_in[3];
  const float* cw = (const float*)d_in[4];
  const float* cb = (const float*)d_in[5];
  const float* xpw = (const float*)d_in[6];
  const float* dtw = (const float*)d_in[7];
  const float* dtb = (const float*)d_in[8];
  const float* alog = (const float*)d_in[9];
  const float* Dv = (const float*)d_in[10];
  const float* ow = (const float*)d_in[11];
  float* out = (float*)d_out;

  const size_t BLE = (size_t)BATCH * LSEQ * DI;       // 8.39M floats
  const size_t XDN = (size_t)BATCH * LSEQ * XDR;      // 393K floats
  const size_t SC = (size_t)BATCH * NC * DI * DSTATE; // 2.10M floats
  float* bufX = (float*)d_ws;       // x_pre -> delta_raw -> g (reused)
  float* bufZ = bufX + BLE;         // z
  float* bufU = bufZ + BLE;         // u
  float* bufXD = bufU + BLE;        // x_dbl (B,L,96)
  float* bufP = bufXD + XDN;        // split-K partials (dead after 4b)
  float* sEnd = bufP;               // scan scratch aliases bufP
  float* sProd = sEnd + SC;
  float* sInit = sProd + SC;

  const int M = BATCH * LSEQ;  // 4096
  dim3 blk(256);

  // 1. x_pre = hs @ w1^T   (MFMA bf16)
  gemm_nt_mfma<<<dim3(DI / 128, M / 128), blk, 0, stream>>>(
      hs, w1, bufX, DM, DM, DM, DI);
  // 2. z = in2 @ w2^T      (MFMA bf16)
  gemm_nt_mfma<<<dim3(DI / 128, M / 128), blk, 0, stream>>>(
      in2, w2, bufZ, DM, DM, DM, DI);
  // 3. u = silu(conv(x_pre) + cb)
  conv_silu_kernel<<<(M * (DI / 4)) / 256, blk, 0, stream>>>(bufX, cw, cb,
                                                             bufU);
  // 4. x_dbl partials = u @ xpw^T, split-K x4  (f32)
  gemm_nt<128, 128, 16, 8, 8><<<dim3(1, M / 128, 4), blk, 0, stream>>>(
      bufU, xpw, bufP, M, XDR, DI / 4, DI, DI, XDR);
  // 4b. reduce partials -> bufXD
  reduce4_kernel<<<(int)((XDN + 255) / 256), blk, 0, stream>>>(bufP, bufXD,
                                                               (int)XDN);
  // 5. delta_raw = dt @ dtw^T  (f32, K=64)
  gemm_nt<128, 128, 16, 8, 8><<<dim3(DI / 128, M / 128), blk, 0, stream>>>(
      bufXD, dtw, bufX, M, DI, DTR, XDR, DTR, DI);
  // 6. chunked scan (in-place on bufX: delta_raw -> g)
  scan_passA<<<(BATCH * DI * DSTATE * NC) / 256, blk, 0, stream>>>(
      bufX, bufU, bufXD, dtb, alog, sEnd, sProd);
  scan_passB<<<(BATCH * DI * DSTATE) / 256, blk, 0, stream>>>(sEnd, sProd,
                                                              sInit);
  scan_passC<<<(BATCH * DI * DSTATE * NC) / 256, blk, 0, stream>>>(
      bufX, bufU, bufZ, bufXD, dtb, alog, Dv, sInit);
  // 7. out = g @ ow^T      (MFMA bf16)
  gemm_nt_mfma<<<dim3(DM / 128, M / 128), blk, 0, stream>>>(
      bufX, ow, out, DI, DI, DI, DM);
}

// Round 8
// 425.035 us; speedup vs baseline: 3.8536x; 1.6254x over previous
//
#include <hip/hip_runtime.h>
#include <cstddef>
#include <cmath>

#define BATCH 2
#define LSEQ 2048
#define DM 1024
#define DSTATE 16
#define DI 2048
#define DTR 64
#define XDR 96   // DTR + 2*DSTATE
#define NC 32    // scan chunks
#define TC 64    // timesteps per chunk (NC*TC == LSEQ)

using f32x4 = __attribute__((ext_vector_type(4))) float;
using bf16x8 = __attribute__((ext_vector_type(8))) short;

__device__ __forceinline__ unsigned short f2bf(float f) {
  union { float f; unsigned int u; } c; c.f = f;
  unsigned int u = c.u;
  return (unsigned short)((u + 0x7FFFu + ((u >> 16) & 1u)) >> 16);  // RNE
}
__device__ __forceinline__ unsigned int pack2(float a, float b) {
  return (unsigned int)f2bf(a) | ((unsigned int)f2bf(b) << 16);
}

// ---------------------------------------------------------------------------
// NT GEMM via bf16 MFMA: C[m,n] = sum_k A[m*lda+k] * B[n*ldb+k], f32 in/out.
// BM=BN=128, BK=32, 256 threads = 4 waves (2x2), 64x64 per wave.
// ---------------------------------------------------------------------------
__global__ __launch_bounds__(256) void gemm_nt_mfma(
    const float* __restrict__ A, const float* __restrict__ B,
    float* __restrict__ C, int K, int lda, int ldb, int ldc) {
  __shared__ __align__(16) unsigned short As[128][40];
  __shared__ __align__(16) unsigned short Bs[128][40];

  const int tid = threadIdx.x;
  const int lane = tid & 63;
  const int wid = tid >> 6;
  const int wm = (wid >> 1) * 64;
  const int wn = (wid & 1) * 64;
  const size_t m0 = (size_t)blockIdx.y * 128;
  const size_t n0 = (size_t)blockIdx.x * 128;

  const int srow = tid >> 1;
  const int skb = (tid & 1) * 16;
  const float* ag = &A[(m0 + srow) * lda + skb];
  const float* bg = &B[(n0 + srow) * ldb + skb];
  uint4* adst = reinterpret_cast<uint4*>(&As[srow][skb]);
  uint4* bdst = reinterpret_cast<uint4*>(&Bs[srow][skb]);

  f32x4 acc[4][4] = {};

  const int fr = lane & 15;
  const int fko = (lane >> 4) * 8;

  for (int k0 = 0; k0 < K; k0 += 32) {
    const float4* ap = reinterpret_cast<const float4*>(ag + k0);
    const float4* bp = reinterpret_cast<const float4*>(bg + k0);
    float4 a0 = ap[0], a1 = ap[1], a2 = ap[2], a3 = ap[3];
    float4 b0 = bp[0], b1 = bp[1], b2 = bp[2], b3 = bp[3];

    adst[0] = make_uint4(pack2(a0.x, a0.y), pack2(a0.z, a0.w),
                         pack2(a1.x, a1.y), pack2(a1.z, a1.w));
    adst[1] = make_uint4(pack2(a2.x, a2.y), pack2(a2.z, a2.w),
                         pack2(a3.x, a3.y), pack2(a3.z, a3.w));
    bdst[0] = make_uint4(pack2(b0.x, b0.y), pack2(b0.z, b0.w),
                         pack2(b1.x, b1.y), pack2(b1.z, b1.w));
    bdst[1] = make_uint4(pack2(b2.x, b2.y), pack2(b2.z, b2.w),
                         pack2(b3.x, b3.y), pack2(b3.z, b3.w));
    __syncthreads();

    bf16x8 af[4], bfr[4];
#pragma unroll
    for (int i = 0; i < 4; ++i) {
      af[i] = *reinterpret_cast<const bf16x8*>(&As[wm + i * 16 + fr][fko]);
      bfr[i] = *reinterpret_cast<const bf16x8*>(&Bs[wn + i * 16 + fr][fko]);
    }
#pragma unroll
    for (int i = 0; i < 4; ++i)
#pragma unroll
      for (int j = 0; j < 4; ++j)
        acc[i][j] = __builtin_amdgcn_mfma_f32_16x16x32_bf16(
            af[i], bfr[j], acc[i][j], 0, 0, 0);
    __syncthreads();
  }

  const int crb = (lane >> 4) * 4;
#pragma unroll
  for (int i = 0; i < 4; ++i) {
    size_t row = m0 + wm + i * 16 + crb;
#pragma unroll
    for (int j = 0; j < 4; ++j) {
      size_t col = n0 + wn + j * 16 + fr;
#pragma unroll
      for (int r = 0; r < 4; ++r)
        C[(row + r) * ldc + col] = acc[i][j][r];
    }
  }
}

// ---------------------------------------------------------------------------
// Tiled f32 GEMM, NT layout, with split-K along blockIdx.z.
// ---------------------------------------------------------------------------
template<int BM, int BN, int BK, int TM, int TN>
__global__ __launch_bounds__(256) void gemm_nt(
    const float* __restrict__ A, const float* __restrict__ B,
    float* __restrict__ C,
    int M, int N, int K, int lda, int ldb, int ldc) {
  constexpr int THREADS = (BM / TM) * (BN / TN);
  static_assert(THREADS == 256, "block must be 256");
  constexpr int PAD = 4;
  __shared__ float As[BK][BM + PAD];
  __shared__ float Bs[BK][BN + PAD];

  A += (size_t)blockIdx.z * K;
  B += (size_t)blockIdx.z * K;
  C += (size_t)blockIdx.z * (size_t)M * ldc;

  const int tid = threadIdx.x;
  const int tc = tid % (BN / TN);
  const int tr = tid / (BN / TN);
  const int m0 = blockIdx.y * BM;
  const int n0 = blockIdx.x * BN;

  float acc[TM][TN];
#pragma unroll
  for (int i = 0; i < TM; ++i)
#pragma unroll
    for (int j = 0; j < TN; ++j) acc[i][j] = 0.f;

  constexpr int AV = BM * BK / 4 / THREADS;
  constexpr int BV = BN * BK / 4 / THREADS;

  for (int k0 = 0; k0 < K; k0 += BK) {
#pragma unroll
    for (int i = 0; i < AV; ++i) {
      int f = tid + i * THREADS;
      int r = f / (BK / 4);
      int c4 = (f % (BK / 4)) * 4;
      int gm = m0 + r, gk = k0 + c4;
      float4 v = make_float4(0.f, 0.f, 0.f, 0.f);
      if (gm < M && gk < K)
        v = *reinterpret_cast<const float4*>(&A[(size_t)gm * lda + gk]);
      As[c4 + 0][r] = v.x;
      As[c4 + 1][r] = v.y;
      As[c4 + 2][r] = v.z;
      As[c4 + 3][r] = v.w;
    }
#pragma unroll
    for (int i = 0; i < BV; ++i) {
      int f = tid + i * THREADS;
      int r = f / (BK / 4);
      int c4 = (f % (BK / 4)) * 4;
      int gn = n0 + r, gk = k0 + c4;
      float4 v = make_float4(0.f, 0.f, 0.f, 0.f);
      if (gn < N && gk < K)
        v = *reinterpret_cast<const float4*>(&B[(size_t)gn * ldb + gk]);
      Bs[c4 + 0][r] = v.x;
      Bs[c4 + 1][r] = v.y;
      Bs[c4 + 2][r] = v.z;
      Bs[c4 + 3][r] = v.w;
    }
    __syncthreads();

#pragma unroll
    for (int k = 0; k < BK; ++k) {
      float a[TM], bb[TN];
#pragma unroll
      for (int h = 0; h < TM; h += 4)
        *reinterpret_cast<float4*>(&a[h]) =
            *reinterpret_cast<const float4*>(&As[k][tr * TM + h]);
#pragma unroll
      for (int h = 0; h < TN; h += 4)
        *reinterpret_cast<float4*>(&bb[h]) =
            *reinterpret_cast<const float4*>(&Bs[k][tc * TN + h]);
#pragma unroll
      for (int i = 0; i < TM; ++i)
#pragma unroll
        for (int j = 0; j < TN; ++j) acc[i][j] = fmaf(a[i], bb[j], acc[i][j]);
    }
    __syncthreads();
  }

#pragma unroll
  for (int i = 0; i < TM; ++i) {
    int gm = m0 + tr * TM + i;
    if (gm >= M) continue;
#pragma unroll
    for (int j4 = 0; j4 < TN; j4 += 4) {
      int gn = n0 + tc * TN + j4;
      if (gn + 3 < N) {
        float4 v = make_float4(acc[i][j4], acc[i][j4 + 1], acc[i][j4 + 2],
                               acc[i][j4 + 3]);
        *reinterpret_cast<float4*>(&C[(size_t)gm * ldc + gn]) = v;
      } else {
#pragma unroll
        for (int j = 0; j < 4; ++j)
          if (gn + j < N) C[(size_t)gm * ldc + gn + j] = acc[i][j4 + j];
      }
    }
  }
}

// 4-way split-K reduction: o[i] = sum_z P[z*n + i]
__global__ __launch_bounds__(256) void reduce4_kernel(
    const float* __restrict__ P, float* __restrict__ o, int n) {
  int i = blockIdx.x * 256 + threadIdx.x;
  if (i < n) o[i] = (P[i] + P[n + i]) + (P[2 * n + i] + P[3 * n + i]);
}

// ---------------------------------------------------------------------------
// Depthwise causal conv (D_CONV=4) + bias + SiLU.  x layout (B, L, E).
// ---------------------------------------------------------------------------
__global__ __launch_bounds__(256) void conv_silu_kernel(
    const float* __restrict__ x, const float* __restrict__ w,
    const float* __restrict__ cb, float* __restrict__ out) {
  int idx = blockIdx.x * 256 + threadIdx.x;
  int e4 = idx % (DI / 4);
  int bl = idx / (DI / 4);
  int l = bl % LSEQ;
  int e = e4 * 4;

  const float4* cw = reinterpret_cast<const float4*>(w);
  float4 w0 = cw[e], w1 = cw[e + 1], w2 = cw[e + 2], w3 = cw[e + 3];
  float4 acc = *reinterpret_cast<const float4*>(&cb[e]);

#define TAPK(K, COMP)                                                       \
  {                                                                         \
    int ls = l - 3 + (K);                                                   \
    if (ls >= 0) {                                                          \
      float4 xv = *reinterpret_cast<const float4*>(                         \
          &x[((size_t)(bl) - 3 + (K)) * DI + e]);                           \
      acc.x = fmaf(xv.x, w0.COMP, acc.x);                                   \
      acc.y = fmaf(xv.y, w1.COMP, acc.y);                                   \
      acc.z = fmaf(xv.z, w2.COMP, acc.z);                                   \
      acc.w = fmaf(xv.w, w3.COMP, acc.w);                                   \
    }                                                                       \
  }
  TAPK(0, x)
  TAPK(1, y)
  TAPK(2, z)
  TAPK(3, w)
#undef TAPK

  acc.x = acc.x / (1.f + expf(-acc.x));
  acc.y = acc.y / (1.f + expf(-acc.y));
  acc.z = acc.z / (1.f + expf(-acc.z));
  acc.w = acc.w / (1.f + expf(-acc.w));
  *reinterpret_cast<float4*>(&out[(size_t)bl * DI + e]) = acc;
}

// ---------------------------------------------------------------------------
// Chunked selective scan, 16 states per thread.
// Thread = (b, e, chunk).  All DSTATE states live in registers; softplus/d
// computed once per step (not x16); y-dot is in-thread (no shuffles).
// Layout of chunk summaries: [(b*NC+c)*DI + e]*16 + n  (n contiguous).
// ---------------------------------------------------------------------------
__device__ __forceinline__ float softplus_fast(float x) {
  float ex = __expf(x);
  return (x > 20.f) ? x : __logf(1.f + ex);
}

__global__ __launch_bounds__(256) void scan_passA(
    const float* __restrict__ draw, const float* __restrict__ u,
    const float* __restrict__ xdbl, const float* __restrict__ dtb,
    const float* __restrict__ A_log, float* __restrict__ sEnd,
    float* __restrict__ sProd) {
  int g = blockIdx.x * 256 + threadIdx.x;  // B*E*NC = 131072 threads
  int e = g & (DI - 1);
  int c = (g >> 11) & (NC - 1);
  int b = g >> 16;

  float nA[DSTATE];
#pragma unroll
  for (int n = 0; n < DSTATE; ++n) nA[n] = -__expf(A_log[e * DSTATE + n]);
  const float bias = dtb[e];

  size_t off = ((size_t)b * LSEQ + c * TC) * DI + e;
  size_t xoff = ((size_t)b * LSEQ + c * TC) * XDR + 64;

  float s[DSTATE], P[DSTATE];
#pragma unroll
  for (int n = 0; n < DSTATE; ++n) { s[n] = 0.f; P[n] = 1.f; }

  // prefetch t=0
  float dr = draw[off];
  float ut = u[off];
  float4 B0 = *reinterpret_cast<const float4*>(&xdbl[xoff]);
  float4 B1 = *reinterpret_cast<const float4*>(&xdbl[xoff + 4]);
  float4 B2 = *reinterpret_cast<const float4*>(&xdbl[xoff + 8]);
  float4 B3 = *reinterpret_cast<const float4*>(&xdbl[xoff + 12]);

  for (int t = 0; t < TC; ++t) {
    float dr_n = 0.f, ut_n = 0.f;
    float4 B0n = {}, B1n = {}, B2n = {}, B3n = {};
    if (t + 1 < TC) {
      dr_n = draw[off + DI];
      ut_n = u[off + DI];
      B0n = *reinterpret_cast<const float4*>(&xdbl[xoff + XDR]);
      B1n = *reinterpret_cast<const float4*>(&xdbl[xoff + XDR + 4]);
      B2n = *reinterpret_cast<const float4*>(&xdbl[xoff + XDR + 8]);
      B3n = *reinterpret_cast<const float4*>(&xdbl[xoff + XDR + 12]);
    }

    float d = softplus_fast(dr + bias);
    float db = d * ut;
    float Bv[DSTATE] = {B0.x, B0.y, B0.z, B0.w, B1.x, B1.y, B1.z, B1.w,
                        B2.x, B2.y, B2.z, B2.w, B3.x, B3.y, B3.z, B3.w};
#pragma unroll
    for (int n = 0; n < DSTATE; ++n) {
      float dA = __expf(d * nA[n]);
      s[n] = fmaf(s[n], dA, db * Bv[n]);
      P[n] *= dA;
    }
    off += DI;
    xoff += XDR;
    dr = dr_n; ut = ut_n;
    B0 = B0n; B1 = B1n; B2 = B2n; B3 = B3n;
  }

  size_t o = (((size_t)b * NC + c) * DI + e) * DSTATE;
  float4* se = reinterpret_cast<float4*>(&sEnd[o]);
  float4* sp = reinterpret_cast<float4*>(&sProd[o]);
  se[0] = make_float4(s[0], s[1], s[2], s[3]);
  se[1] = make_float4(s[4], s[5], s[6], s[7]);
  se[2] = make_float4(s[8], s[9], s[10], s[11]);
  se[3] = make_float4(s[12], s[13], s[14], s[15]);
  sp[0] = make_float4(P[0], P[1], P[2], P[3]);
  sp[1] = make_float4(P[4], P[5], P[6], P[7]);
  sp[2] = make_float4(P[8], P[9], P[10], P[11]);
  sp[3] = make_float4(P[12], P[13], P[14], P[15]);
}

__global__ __launch_bounds__(256) void scan_passB(
    const float* __restrict__ sEnd, const float* __restrict__ sProd,
    float* __restrict__ sInit) {
  int g = blockIdx.x * 256 + threadIdx.x;  // 65,536 threads
  int n = g & 15;
  int e = (g >> 4) & (DI - 1);
  int b = g >> 15;
  float s = 0.f;
  for (int c = 0; c < NC; ++c) {
    size_t o = (((size_t)b * NC + c) * DI + e) * DSTATE + n;
    sInit[o] = s;
    s = fmaf(s, sProd[o], sEnd[o]);  // s = sEnd[c] + P[c]*s
  }
}

__global__ __launch_bounds__(256) void scan_passC(
    float* dg, const float* __restrict__ u, const float* __restrict__ z,
    const float* __restrict__ xdbl, const float* __restrict__ dtb,
    const float* __restrict__ A_log, const float* __restrict__ Dv,
    const float* __restrict__ sInit) {
  int g = blockIdx.x * 256 + threadIdx.x;  // B*E*NC = 131072 threads
  int e = g & (DI - 1);
  int c = (g >> 11) & (NC - 1);
  int b = g >> 16;

  float nA[DSTATE];
#pragma unroll
  for (int n = 0; n < DSTATE; ++n) nA[n] = -__expf(A_log[e * DSTATE + n]);
  const float bias = dtb[e];
  const float Dval = Dv[e];

  size_t off = ((size_t)b * LSEQ + c * TC) * DI + e;
  size_t xoff = ((size_t)b * LSEQ + c * TC) * XDR + 64;

  float s[DSTATE];
  {
    size_t o = (((size_t)b * NC + c) * DI + e) * DSTATE;
    const float4* si = reinterpret_cast<const float4*>(&sInit[o]);
    float4 s0 = si[0], s1 = si[1], s2 = si[2], s3 = si[3];
    s[0] = s0.x; s[1] = s0.y; s[2] = s0.z; s[3] = s0.w;
    s[4] = s1.x; s[5] = s1.y; s[6] = s1.z; s[7] = s1.w;
    s[8] = s2.x; s[9] = s2.y; s[10] = s2.z; s[11] = s2.w;
    s[12] = s3.x; s[13] = s3.y; s[14] = s3.z; s[15] = s3.w;
  }

  // prefetch t=0
  float dr = dg[off];
  float ut = u[off];
  float zt = z[off];
  float4 B0 = *reinterpret_cast<const float4*>(&xdbl[xoff]);
  float4 B1 = *reinterpret_cast<const float4*>(&xdbl[xoff + 4]);
  float4 B2 = *reinterpret_cast<const float4*>(&xdbl[xoff + 8]);
  float4 B3 = *reinterpret_cast<const float4*>(&xdbl[xoff + 12]);
  float4 C0 = *reinterpret_cast<const float4*>(&xdbl[xoff + 16]);
  float4 C1 = *reinterpret_cast<const float4*>(&xdbl[xoff + 20]);
  float4 C2 = *reinterpret_cast<const float4*>(&xdbl[xoff + 24]);
  float4 C3 = *reinterpret_cast<const float4*>(&xdbl[xoff + 28]);

  for (int t = 0; t < TC; ++t) {
    float dr_n = 0.f, ut_n = 0.f, zt_n = 0.f;
    float4 B0n = {}, B1n = {}, B2n = {}, B3n = {};
    float4 C0n = {}, C1n = {}, C2n = {}, C3n = {};
    if (t + 1 < TC) {
      dr_n = dg[off + DI];
      ut_n = u[off + DI];
      zt_n = z[off + DI];
      B0n = *reinterpret_cast<const float4*>(&xdbl[xoff + XDR]);
      B1n = *reinterpret_cast<const float4*>(&xdbl[xoff + XDR + 4]);
      B2n = *reinterpret_cast<const float4*>(&xdbl[xoff + XDR + 8]);
      B3n = *reinterpret_cast<const float4*>(&xdbl[xoff + XDR + 12]);
      C0n = *reinterpret_cast<const float4*>(&xdbl[xoff + XDR + 16]);
      C1n = *reinterpret_cast<const float4*>(&xdbl[xoff + XDR + 20]);
      C2n = *reinterpret_cast<const float4*>(&xdbl[xoff + XDR + 24]);
      C3n = *reinterpret_cast<const float4*>(&xdbl[xoff + XDR + 28]);
    }

    float d = softplus_fast(dr + bias);
    float db = d * ut;
    float Bv[DSTATE] = {B0.x, B0.y, B0.z, B0.w, B1.x, B1.y, B1.z, B1.w,
                        B2.x, B2.y, B2.z, B2.w, B3.x, B3.y, B3.z, B3.w};
    float Cv[DSTATE] = {C0.x, C0.y, C0.z, C0.w, C1.x, C1.y, C1.z, C1.w,
                        C2.x, C2.y, C2.z, C2.w, C3.x, C3.y, C3.z, C3.w};
    float y = 0.f;
#pragma unroll
    for (int n = 0; n < DSTATE; ++n) {
      float dA = __expf(d * nA[n]);
      s[n] = fmaf(s[n], dA, db * Bv[n]);
      y = fmaf(s[n], Cv[n], y);
    }
    float gate = zt / (1.f + __expf(-zt));
    dg[off] = (y + Dval * ut) * gate;

    off += DI;
    xoff += XDR;
    dr = dr_n; ut = ut_n; zt = zt_n;
    B0 = B0n; B1 = B1n; B2 = B2n; B3 = B3n;
    C0 = C0n; C1 = C1n; C2 = C2n; C3 = C3n;
  }
}

// ---------------------------------------------------------------------------
extern "C" void kernel_launch(void* const* d_in, const int* in_sizes, int n_in,
                              void* d_out, int out_size, void* d_ws,
                              size_t ws_size, hipStream_t stream) {
  const float* hs = (const float*)d_in[0];
  const float* in2 = (const float*)d_in[1];
  const float* w1 = (const float*)d_in[2];
  const float* w2 = (const float*)d_in[3];
  const float* cw = (const float*)d_in[4];
  const float* cb = (const float*)d_in[5];
  const float* xpw = (const float*)d_in[6];
  const float* dtw = (const float*)d_in[7];
  const float* dtb = (const float*)d_in[8];
  const float* alog = (const float*)d_in[9];
  const float* Dv = (const float*)d_in[10];
  const float* ow = (const float*)d_in[11];
  float* out = (float*)d_out;

  const size_t BLE = (size_t)BATCH * LSEQ * DI;       // 8.39M floats
  const size_t XDN = (size_t)BATCH * LSEQ * XDR;      // 393K floats
  const size_t SC = (size_t)BATCH * NC * DI * DSTATE; // 2.10M floats
  float* bufX = (float*)d_ws;       // x_pre -> delta_raw -> g (reused)
  float* bufZ = bufX + BLE;         // z
  float* bufU = bufZ + BLE;         // u
  float* bufXD = bufU + BLE;        // x_dbl (B,L,96)
  float* bufP = bufXD + XDN;        // split-K partials (dead after 4b)
  float* sEnd = bufP;               // scan scratch aliases bufP
  float* sProd = sEnd + SC;
  float* sInit = sProd + SC;

  const int M = BATCH * LSEQ;  // 4096
  dim3 blk(256);

  // 1. x_pre = hs @ w1^T   (MFMA bf16)
  gemm_nt_mfma<<<dim3(DI / 128, M / 128), blk, 0, stream>>>(
      hs, w1, bufX, DM, DM, DM, DI);
  // 2. z = in2 @ w2^T      (MFMA bf16)
  gemm_nt_mfma<<<dim3(DI / 128, M / 128), blk, 0, stream>>>(
      in2, w2, bufZ, DM, DM, DM, DI);
  // 3. u = silu(conv(x_pre) + cb)
  conv_silu_kernel<<<(M * (DI / 4)) / 256, blk, 0, stream>>>(bufX, cw, cb,
                                                             bufU);
  // 4. x_dbl partials = u @ xpw^T, split-K x4  (f32)
  gemm_nt<128, 128, 16, 8, 8><<<dim3(1, M / 128, 4), blk, 0, stream>>>(
      bufU, xpw, bufP, M, XDR, DI / 4, DI, DI, XDR);
  // 4b. reduce partials -> bufXD
  reduce4_kernel<<<(int)((XDN + 255) / 256), blk, 0, stream>>>(bufP, bufXD,
                                                               (int)XDN);
  // 5. delta_raw = dt @ dtw^T  (f32, K=64)
  gemm_nt<128, 128, 16, 8, 8><<<dim3(DI / 128, M / 128), blk, 0, stream>>>(
      bufXD, dtw, bufX, M, DI, DTR, XDR, DTR, DI);
  // 6. chunked scan (in-place on bufX: delta_raw -> g)
  scan_passA<<<(BATCH * DI * NC) / 256, blk, 0, stream>>>(
      bufX, bufU, bufXD, dtb, alog, sEnd, sProd);
  scan_passB<<<(BATCH * DI * DSTATE) / 256, blk, 0, stream>>>(sEnd, sProd,
                                                              sInit);
  scan_passC<<<(BATCH * DI * NC) / 256, blk, 0, stream>>>(
      bufX, bufU, bufZ, bufXD, dtb, alog, Dv, sInit);
  // 7. out = g @ ow^T      (MFMA bf16)
  gemm_nt_mfma<<<dim3(DM / 128, M / 128), blk, 0, stream>>>(
      bufX, ow, out, DI, DI, DI, DM);
}

// Round 9
// 342.341 us; speedup vs baseline: 4.7845x; 1.2416x over previous
//
#include <hip/hip_runtime.h>
#include <cstddef>
#include <cmath>

#define BATCH 2
#define LSEQ 2048
#define DM 1024
#define DSTATE 16
#define DI 2048
#define DTR 64
#define XDR 96   // DTR + 2*DSTATE
#define NC 32    // scan chunks
#define TC 64    // timesteps per chunk (NC*TC == LSEQ)

using f32x4 = __attribute__((ext_vector_type(4))) float;
using bf16x8 = __attribute__((ext_vector_type(8))) short;

__device__ __forceinline__ unsigned short f2bf(float f) {
  union { float f; unsigned int u; } c; c.f = f;
  unsigned int u = c.u;
  return (unsigned short)((u + 0x7FFFu + ((u >> 16) & 1u)) >> 16);  // RNE
}
__device__ __forceinline__ unsigned int pack2(float a, float b) {
  return (unsigned int)f2bf(a) | ((unsigned int)f2bf(b) << 16);
}

__device__ __forceinline__ void gl_lds16(const void* g, void* l) {
  __builtin_amdgcn_global_load_lds(
      (const __attribute__((address_space(1))) void*)g,
      (__attribute__((address_space(3))) void*)l, 16, 0, 0);
}

// ---------------------------------------------------------------------------
// f32 -> bf16 conversion, 8 elems/thread (exact-size grids).
// ---------------------------------------------------------------------------
__global__ __launch_bounds__(256) void cvt_bf16_kernel(
    const float* __restrict__ s, unsigned short* __restrict__ d, int n8) {
  int i = blockIdx.x * 256 + threadIdx.x;
  if (i >= n8) return;
  const float4* sp = reinterpret_cast<const float4*>(s) + (size_t)i * 2;
  float4 a = sp[0], b = sp[1];
  uint4 v = make_uint4(pack2(a.x, a.y), pack2(a.z, a.w), pack2(b.x, b.y),
                       pack2(b.z, b.w));
  *(reinterpret_cast<uint4*>(d) + i) = v;
}

// ---------------------------------------------------------------------------
// NT GEMM, bf16 inputs, f32 out: C[m,n] = sum_k A[m*lda+k]*B[n*ldb+k].
// BM=BN=128, BK=64, 256 thr = 4 waves (2x2), 64x64/wave, 32 MFMA/K-step/wave.
// Staging: global_load_lds dwordx4, linear LDS dest, PRE-SWIZZLED global
// source (slot ^= row&7); ds_read applies the same XOR -> <=2-way conflicts.
// XCD-aware bijective block swizzle (nwg % 8 == 0 at all call sites).
// Requires M%128==0, N%128==0, K%64==0.
// ---------------------------------------------------------------------------
__global__ __launch_bounds__(256) void gemm_bf16(
    const unsigned short* __restrict__ A, const unsigned short* __restrict__ B,
    float* __restrict__ C, int K, int lda, int ldb, int ldc) {
  __shared__ __align__(16) unsigned short As[128][64];
  __shared__ __align__(16) unsigned short Bs[128][64];

  const int tid = threadIdx.x;
  const int lane = tid & 63;
  const int w = tid >> 6;

  // XCD swizzle: each XCD gets a contiguous chunk of row-major tile ids.
  const int gx = gridDim.x;
  const int nwg = gx * gridDim.y;
  const int id = blockIdx.y * gx + blockIdx.x;
  const int cpx = nwg >> 3;
  const int lt = (id & 7) * cpx + (id >> 3);
  const size_t m0 = (size_t)(lt / gx) * 128;
  const size_t n0 = (size_t)(lt % gx) * 128;

  // staging geometry: wave w stages rows [w*32, w*32+32) of both tiles,
  // 4 instrs each (8 rows / 1KB per instr).  lane covers row (lane>>3),
  // slot (lane&7); source slot pre-swizzled by row&7 == lane>>3.
  const int rsub = lane >> 3;
  const int sslot = (lane & 7) ^ rsub;
  const unsigned short* Ab = A + m0 * lda + (size_t)rsub * lda + sslot * 8;
  const unsigned short* Bb = B + n0 * ldb + (size_t)rsub * ldb + sslot * 8;

  f32x4 acc[4][4] = {};

  const int fr = lane & 15;
  const int q = lane >> 4;   // k-quarter
  const int f7 = fr & 7;

  for (int k0 = 0; k0 < K; k0 += 64) {
#pragma unroll
    for (int i = 0; i < 4; ++i) {
      const int r0 = w * 32 + i * 8;
      gl_lds16(Ab + (size_t)r0 * lda + k0, &As[r0][0]);
      gl_lds16(Bb + (size_t)r0 * ldb + k0, &Bs[r0][0]);
    }
    __syncthreads();

    bf16x8 af[4][2], bf_[4][2];
#pragma unroll
    for (int i = 0; i < 4; ++i) {
#pragma unroll
      for (int kk = 0; kk < 2; ++kk) {
        const int sA = (((kk * 4 + q) ^ f7) << 3);
        af[i][kk] = *reinterpret_cast<const bf16x8*>(
            &As[(w >> 1) * 64 + i * 16 + fr][sA]);
        bf_[i][kk] = *reinterpret_cast<const bf16x8*>(
            &Bs[(w & 1) * 64 + i * 16 + fr][sA]);
      }
    }
#pragma unroll
    for (int kk = 0; kk < 2; ++kk)
#pragma unroll
      for (int i = 0; i < 4; ++i)
#pragma unroll
        for (int j = 0; j < 4; ++j)
          acc[i][j] = __builtin_amdgcn_mfma_f32_16x16x32_bf16(
              af[i][kk], bf_[j][kk], acc[i][j], 0, 0, 0);
    __syncthreads();
  }

  // C/D layout: col = lane&15, row = (lane>>4)*4 + reg
  const int crb = q * 4;
#pragma unroll
  for (int i = 0; i < 4; ++i) {
    size_t row = m0 + (w >> 1) * 64 + i * 16 + crb;
#pragma unroll
    for (int j = 0; j < 4; ++j) {
      size_t col = n0 + (w & 1) * 64 + j * 16 + fr;
#pragma unroll
      for (int r = 0; r < 4; ++r)
        C[(row + r) * ldc + col] = acc[i][j][r];
    }
  }
}

// ---------------------------------------------------------------------------
// Tiled f32 GEMM, NT layout, with split-K along blockIdx.z.
// ---------------------------------------------------------------------------
template<int BM, int BN, int BK, int TM, int TN>
__global__ __launch_bounds__(256) void gemm_nt(
    const float* __restrict__ A, const float* __restrict__ B,
    float* __restrict__ C,
    int M, int N, int K, int lda, int ldb, int ldc) {
  constexpr int THREADS = (BM / TM) * (BN / TN);
  static_assert(THREADS == 256, "block must be 256");
  constexpr int PAD = 4;
  __shared__ float As[BK][BM + PAD];
  __shared__ float Bs[BK][BN + PAD];

  A += (size_t)blockIdx.z * K;
  B += (size_t)blockIdx.z * K;
  C += (size_t)blockIdx.z * (size_t)M * ldc;

  const int tid = threadIdx.x;
  const int tc = tid % (BN / TN);
  const int tr = tid / (BN / TN);
  const int m0 = blockIdx.y * BM;
  const int n0 = blockIdx.x * BN;

  float acc[TM][TN];
#pragma unroll
  for (int i = 0; i < TM; ++i)
#pragma unroll
    for (int j = 0; j < TN; ++j) acc[i][j] = 0.f;

  constexpr int AV = BM * BK / 4 / THREADS;
  constexpr int BV = BN * BK / 4 / THREADS;

  for (int k0 = 0; k0 < K; k0 += BK) {
#pragma unroll
    for (int i = 0; i < AV; ++i) {
      int f = tid + i * THREADS;
      int r = f / (BK / 4);
      int c4 = (f % (BK / 4)) * 4;
      int gm = m0 + r, gk = k0 + c4;
      float4 v = make_float4(0.f, 0.f, 0.f, 0.f);
      if (gm < M && gk < K)
        v = *reinterpret_cast<const float4*>(&A[(size_t)gm * lda + gk]);
      As[c4 + 0][r] = v.x;
      As[c4 + 1][r] = v.y;
      As[c4 + 2][r] = v.z;
      As[c4 + 3][r] = v.w;
    }
#pragma unroll
    for (int i = 0; i < BV; ++i) {
      int f = tid + i * THREADS;
      int r = f / (BK / 4);
      int c4 = (f % (BK / 4)) * 4;
      int gn = n0 + r, gk = k0 + c4;
      float4 v = make_float4(0.f, 0.f, 0.f, 0.f);
      if (gn < N && gk < K)
        v = *reinterpret_cast<const float4*>(&B[(size_t)gn * ldb + gk]);
      Bs[c4 + 0][r] = v.x;
      Bs[c4 + 1][r] = v.y;
      Bs[c4 + 2][r] = v.z;
      Bs[c4 + 3][r] = v.w;
    }
    __syncthreads();

#pragma unroll
    for (int k = 0; k < BK; ++k) {
      float a[TM], bb[TN];
#pragma unroll
      for (int h = 0; h < TM; h += 4)
        *reinterpret_cast<float4*>(&a[h]) =
            *reinterpret_cast<const float4*>(&As[k][tr * TM + h]);
#pragma unroll
      for (int h = 0; h < TN; h += 4)
        *reinterpret_cast<float4*>(&bb[h]) =
            *reinterpret_cast<const float4*>(&Bs[k][tc * TN + h]);
#pragma unroll
      for (int i = 0; i < TM; ++i)
#pragma unroll
        for (int j = 0; j < TN; ++j) acc[i][j] = fmaf(a[i], bb[j], acc[i][j]);
    }
    __syncthreads();
  }

#pragma unroll
  for (int i = 0; i < TM; ++i) {
    int gm = m0 + tr * TM + i;
    if (gm >= M) continue;
#pragma unroll
    for (int j4 = 0; j4 < TN; j4 += 4) {
      int gn = n0 + tc * TN + j4;
      if (gn + 3 < N) {
        float4 v = make_float4(acc[i][j4], acc[i][j4 + 1], acc[i][j4 + 2],
                               acc[i][j4 + 3]);
        *reinterpret_cast<float4*>(&C[(size_t)gm * ldc + gn]) = v;
      } else {
#pragma unroll
        for (int j = 0; j < 4; ++j)
          if (gn + j < N) C[(size_t)gm * ldc + gn + j] = acc[i][j4 + j];
      }
    }
  }
}

// 4-way split-K reduction: o[i] = sum_z P[z*n + i]
__global__ __launch_bounds__(256) void reduce4_kernel(
    const float* __restrict__ P, float* __restrict__ o, int n) {
  int i = blockIdx.x * 256 + threadIdx.x;
  if (i < n) o[i] = (P[i] + P[n + i]) + (P[2 * n + i] + P[3 * n + i]);
}

// ---------------------------------------------------------------------------
// Depthwise causal conv (D_CONV=4) + bias + SiLU.  x layout (B, L, E).
// ---------------------------------------------------------------------------
__global__ __launch_bounds__(256) void conv_silu_kernel(
    const float* __restrict__ x, const float* __restrict__ w,
    const float* __restrict__ cb, float* __restrict__ out) {
  int idx = blockIdx.x * 256 + threadIdx.x;
  int e4 = idx % (DI / 4);
  int bl = idx / (DI / 4);
  int l = bl % LSEQ;
  int e = e4 * 4;

  const float4* cw = reinterpret_cast<const float4*>(w);
  float4 w0 = cw[e], w1 = cw[e + 1], w2 = cw[e + 2], w3 = cw[e + 3];
  float4 acc = *reinterpret_cast<const float4*>(&cb[e]);

#define TAPK(K, COMP)                                                       \
  {                                                                         \
    int ls = l - 3 + (K);                                                   \
    if (ls >= 0) {                                                          \
      float4 xv = *reinterpret_cast<const float4*>(                         \
          &x[((size_t)(bl) - 3 + (K)) * DI + e]);                           \
      acc.x = fmaf(xv.x, w0.COMP, acc.x);                                   \
      acc.y = fmaf(xv.y, w1.COMP, acc.y);                                   \
      acc.z = fmaf(xv.z, w2.COMP, acc.z);                                   \
      acc.w = fmaf(xv.w, w3.COMP, acc.w);                                   \
    }                                                                       \
  }
  TAPK(0, x)
  TAPK(1, y)
  TAPK(2, z)
  TAPK(3, w)
#undef TAPK

  acc.x = acc.x / (1.f + expf(-acc.x));
  acc.y = acc.y / (1.f + expf(-acc.y));
  acc.z = acc.z / (1.f + expf(-acc.z));
  acc.w = acc.w / (1.f + expf(-acc.w));
  *reinterpret_cast<float4*>(&out[(size_t)bl * DI + e]) = acc;
}

// ---------------------------------------------------------------------------
// Chunked selective scan, 16 states per thread (see round-8 notes).
// ---------------------------------------------------------------------------
__device__ __forceinline__ float softplus_fast(float x) {
  float ex = __expf(x);
  return (x > 20.f) ? x : __logf(1.f + ex);
}

__global__ __launch_bounds__(256) void scan_passA(
    const float* __restrict__ draw, const float* __restrict__ u,
    const float* __restrict__ xdbl, const float* __restrict__ dtb,
    const float* __restrict__ A_log, float* __restrict__ sEnd,
    float* __restrict__ sProd) {
  int g = blockIdx.x * 256 + threadIdx.x;  // B*E*NC = 131072 threads
  int e = g & (DI - 1);
  int c = (g >> 11) & (NC - 1);
  int b = g >> 16;

  float nA[DSTATE];
#pragma unroll
  for (int n = 0; n < DSTATE; ++n) nA[n] = -__expf(A_log[e * DSTATE + n]);
  const float bias = dtb[e];

  size_t off = ((size_t)b * LSEQ + c * TC) * DI + e;
  size_t xoff = ((size_t)b * LSEQ + c * TC) * XDR + 64;

  float s[DSTATE], P[DSTATE];
#pragma unroll
  for (int n = 0; n < DSTATE; ++n) { s[n] = 0.f; P[n] = 1.f; }

  float dr = draw[off];
  float ut = u[off];
  float4 B0 = *reinterpret_cast<const float4*>(&xdbl[xoff]);
  float4 B1 = *reinterpret_cast<const float4*>(&xdbl[xoff + 4]);
  float4 B2 = *reinterpret_cast<const float4*>(&xdbl[xoff + 8]);
  float4 B3 = *reinterpret_cast<const float4*>(&xdbl[xoff + 12]);

  for (int t = 0; t < TC; ++t) {
    float dr_n = 0.f, ut_n = 0.f;
    float4 B0n = {}, B1n = {}, B2n = {}, B3n = {};
    if (t + 1 < TC) {
      dr_n = draw[off + DI];
      ut_n = u[off + DI];
      B0n = *reinterpret_cast<const float4*>(&xdbl[xoff + XDR]);
      B1n = *reinterpret_cast<const float4*>(&xdbl[xoff + XDR + 4]);
      B2n = *reinterpret_cast<const float4*>(&xdbl[xoff + XDR + 8]);
      B3n = *reinterpret_cast<const float4*>(&xdbl[xoff + XDR + 12]);
    }

    float d = softplus_fast(dr + bias);
    float db = d * ut;
    float Bv[DSTATE] = {B0.x, B0.y, B0.z, B0.w, B1.x, B1.y, B1.z, B1.w,
                        B2.x, B2.y, B2.z, B2.w, B3.x, B3.y, B3.z, B3.w};
#pragma unroll
    for (int n = 0; n < DSTATE; ++n) {
      float dA = __expf(d * nA[n]);
      s[n] = fmaf(s[n], dA, db * Bv[n]);
      P[n] *= dA;
    }
    off += DI;
    xoff += XDR;
    dr = dr_n; ut = ut_n;
    B0 = B0n; B1 = B1n; B2 = B2n; B3 = B3n;
  }

  size_t o = (((size_t)b * NC + c) * DI + e) * DSTATE;
  float4* se = reinterpret_cast<float4*>(&sEnd[o]);
  float4* sp = reinterpret_cast<float4*>(&sProd[o]);
  se[0] = make_float4(s[0], s[1], s[2], s[3]);
  se[1] = make_float4(s[4], s[5], s[6], s[7]);
  se[2] = make_float4(s[8], s[9], s[10], s[11]);
  se[3] = make_float4(s[12], s[13], s[14], s[15]);
  sp[0] = make_float4(P[0], P[1], P[2], P[3]);
  sp[1] = make_float4(P[4], P[5], P[6], P[7]);
  sp[2] = make_float4(P[8], P[9], P[10], P[11]);
  sp[3] = make_float4(P[12], P[13], P[14], P[15]);
}

__global__ __launch_bounds__(256) void scan_passB(
    const float* __restrict__ sEnd, const float* __restrict__ sProd,
    float* __restrict__ sInit) {
  int g = blockIdx.x * 256 + threadIdx.x;  // 65,536 threads
  int n = g & 15;
  int e = (g >> 4) & (DI - 1);
  int b = g >> 15;
  float s = 0.f;
  for (int c = 0; c < NC; ++c) {
    size_t o = (((size_t)b * NC + c) * DI + e) * DSTATE + n;
    sInit[o] = s;
    s = fmaf(s, sProd[o], sEnd[o]);
  }
}

__global__ __launch_bounds__(256) void scan_passC(
    const float* __restrict__ dg, const float* __restrict__ u,
    const float* __restrict__ z, const float* __restrict__ xdbl,
    const float* __restrict__ dtb, const float* __restrict__ A_log,
    const float* __restrict__ Dv, const float* __restrict__ sInit,
    unsigned short* __restrict__ gOut) {
  int g = blockIdx.x * 256 + threadIdx.x;  // B*E*NC = 131072 threads
  int e = g & (DI - 1);
  int c = (g >> 11) & (NC - 1);
  int b = g >> 16;

  float nA[DSTATE];
#pragma unroll
  for (int n = 0; n < DSTATE; ++n) nA[n] = -__expf(A_log[e * DSTATE + n]);
  const float bias = dtb[e];
  const float Dval = Dv[e];

  size_t off = ((size_t)b * LSEQ + c * TC) * DI + e;
  size_t xoff = ((size_t)b * LSEQ + c * TC) * XDR + 64;

  float s[DSTATE];
  {
    size_t o = (((size_t)b * NC + c) * DI + e) * DSTATE;
    const float4* si = reinterpret_cast<const float4*>(&sInit[o]);
    float4 s0 = si[0], s1 = si[1], s2 = si[2], s3 = si[3];
    s[0] = s0.x; s[1] = s0.y; s[2] = s0.z; s[3] = s0.w;
    s[4] = s1.x; s[5] = s1.y; s[6] = s1.z; s[7] = s1.w;
    s[8] = s2.x; s[9] = s2.y; s[10] = s2.z; s[11] = s2.w;
    s[12] = s3.x; s[13] = s3.y; s[14] = s3.z; s[15] = s3.w;
  }

  float dr = dg[off];
  float ut = u[off];
  float zt = z[off];
  float4 B0 = *reinterpret_cast<const float4*>(&xdbl[xoff]);
  float4 B1 = *reinterpret_cast<const float4*>(&xdbl[xoff + 4]);
  float4 B2 = *reinterpret_cast<const float4*>(&xdbl[xoff + 8]);
  float4 B3 = *reinterpret_cast<const float4*>(&xdbl[xoff + 12]);
  float4 C0 = *reinterpret_cast<const float4*>(&xdbl[xoff + 16]);
  float4 C1 = *reinterpret_cast<const float4*>(&xdbl[xoff + 20]);
  float4 C2 = *reinterpret_cast<const float4*>(&xdbl[xoff + 24]);
  float4 C3 = *reinterpret_cast<const float4*>(&xdbl[xoff + 28]);

  for (int t = 0; t < TC; ++t) {
    float dr_n = 0.f, ut_n = 0.f, zt_n = 0.f;
    float4 B0n = {}, B1n = {}, B2n = {}, B3n = {};
    float4 C0n = {}, C1n = {}, C2n = {}, C3n = {};
    if (t + 1 < TC) {
      dr_n = dg[off + DI];
      ut_n = u[off + DI];
      zt_n = z[off + DI];
      B0n = *reinterpret_cast<const float4*>(&xdbl[xoff + XDR]);
      B1n = *reinterpret_cast<const float4*>(&xdbl[xoff + XDR + 4]);
      B2n = *reinterpret_cast<const float4*>(&xdbl[xoff + XDR + 8]);
      B3n = *reinterpret_cast<const float4*>(&xdbl[xoff + XDR + 12]);
      C0n = *reinterpret_cast<const float4*>(&xdbl[xoff + XDR + 16]);
      C1n = *reinterpret_cast<const float4*>(&xdbl[xoff + XDR + 20]);
      C2n = *reinterpret_cast<const float4*>(&xdbl[xoff + XDR + 24]);
      C3n = *reinterpret_cast<const float4*>(&xdbl[xoff + XDR + 28]);
    }

    float d = softplus_fast(dr + bias);
    float db = d * ut;
    float Bv[DSTATE] = {B0.x, B0.y, B0.z, B0.w, B1.x, B1.y, B1.z, B1.w,
                        B2.x, B2.y, B2.z, B2.w, B3.x, B3.y, B3.z, B3.w};
    float Cv[DSTATE] = {C0.x, C0.y, C0.z, C0.w, C1.x, C1.y, C1.z, C1.w,
                        C2.x, C2.y, C2.z, C2.w, C3.x, C3.y, C3.z, C3.w};
    float y = 0.f;
#pragma unroll
    for (int n = 0; n < DSTATE; ++n) {
      float dA = __expf(d * nA[n]);
      s[n] = fmaf(s[n], dA, db * Bv[n]);
      y = fmaf(s[n], Cv[n], y);
    }
    float gate = zt / (1.f + __expf(-zt));
    gOut[off] = f2bf((y + Dval * ut) * gate);

    off += DI;
    xoff += XDR;
    dr = dr_n; ut = ut_n; zt = zt_n;
    B0 = B0n; B1 = B1n; B2 = B2n; B3 = B3n;
    C0 = C0n; C1 = C1n; C2 = C2n; C3 = C3n;
  }
}

// ---------------------------------------------------------------------------
extern "C" void kernel_launch(void* const* d_in, const int* in_sizes, int n_in,
                              void* d_out, int out_size, void* d_ws,
                              size_t ws_size, hipStream_t stream) {
  const float* hs = (const float*)d_in[0];
  const float* in2 = (const float*)d_in[1];
  const float* w1 = (const float*)d_in[2];
  const float* w2 = (const float*)d_in[3];
  const float* cw = (const float*)d_in[4];
  const float* cb = (const float*)d_in[5];
  const float* xpw = (const float*)d_in[6];
  const float* dtw = (const float*)d_in[7];
  const float* dtb = (const float*)d_in[8];
  const float* alog = (const float*)d_in[9];
  const float* Dv = (const float*)d_in[10];
  const float* ow = (const float*)d_in[11];
  float* out = (float*)d_out;

  const size_t BLE = (size_t)BATCH * LSEQ * DI;        // 8,388,608
  const size_t BLM = (size_t)BATCH * LSEQ * DM;        // 4,194,304
  const size_t XDN = (size_t)BATCH * LSEQ * XDR;       // 393,216
  const size_t WN = (size_t)DI * DM;                   // 2,097,152
  const size_t SC = (size_t)BATCH * NC * DI * DSTATE;  // 2,097,152

  float* bufX = (float*)d_ws;       // x_pre -> delta_raw
  float* bufZ = bufX + BLE;         // z  (also hosts hsb before G2)
  float* bufU = bufZ + BLE;         // u  (also hosts in2b before conv)
  float* bufXD = bufU + BLE;        // x_dbl (B,L,96)
  float* R = bufXD + XDN;           // sequentially-reused scratch region
  // R timeline: [wb1|wb2] -> bufP -> [sEnd|sProd|sInit] -> [bufG .. | owb]
  unsigned short* wb1 = (unsigned short*)R;            // WN ushorts
  unsigned short* wb2 = wb1 + WN;
  float* bufP = R;                                     // 4*XDN floats
  float* sEnd = R;
  float* sProd = R + SC;
  float* sInit = R + 2 * SC;
  unsigned short* bufG = (unsigned short*)R;           // BLE ushorts (=2*SC f)
  unsigned short* owb = (unsigned short*)(R + 2 * SC); // WN ushorts
  unsigned short* hsb = (unsigned short*)bufZ;         // BLM ushorts
  unsigned short* in2b = (unsigned short*)bufU;        // BLM ushorts

  const int M = BATCH * LSEQ;  // 4096
  dim3 blk(256);

  // 0. convert GEMM operands to bf16
  cvt_bf16_kernel<<<(int)(BLM / 8 / 256), blk, 0, stream>>>(hs, hsb,
                                                            (int)(BLM / 8));
  cvt_bf16_kernel<<<(int)(BLM / 8 / 256), blk, 0, stream>>>(in2, in2b,
                                                            (int)(BLM / 8));
  cvt_bf16_kernel<<<(int)(WN / 8 / 256), blk, 0, stream>>>(w1, wb1,
                                                           (int)(WN / 8));
  cvt_bf16_kernel<<<(int)(WN / 8 / 256), blk, 0, stream>>>(w2, wb2,
                                                           (int)(WN / 8));
  // 1. x_pre = hs @ w1^T
  gemm_bf16<<<dim3(DI / 128, M / 128), blk, 0, stream>>>(hsb, wb1, bufX, DM,
                                                         DM, DM, DI);
  // 2. z = in2 @ w2^T   (writes bufZ; hsb dead)
  gemm_bf16<<<dim3(DI / 128, M / 128), blk, 0, stream>>>(in2b, wb2, bufZ, DM,
                                                         DM, DM, DI);
  // 3. u = silu(conv(x_pre) + cb)   (writes bufU; in2b dead)
  conv_silu_kernel<<<(M * (DI / 4)) / 256, blk, 0, stream>>>(bufX, cw, cb,
                                                             bufU);
  // 4. x_dbl partials = u @ xpw^T, split-K x4  (f32; wb1/wb2 dead)
  gemm_nt<128, 128, 16, 8, 8><<<dim3(1, M / 128, 4), blk, 0, stream>>>(
      bufU, xpw, bufP, M, XDR, DI / 4, DI, DI, XDR);
  reduce4_kernel<<<(int)((XDN + 255) / 256), blk, 0, stream>>>(bufP, bufXD,
                                                               (int)XDN);
  // 5. delta_raw = dt @ dtw^T  (f32, K=64)
  gemm_nt<128, 128, 16, 8, 8><<<dim3(DI / 128, M / 128), blk, 0, stream>>>(
      bufXD, dtw, bufX, M, DI, DTR, XDR, DTR, DI);
  // 6. chunked scan; passC emits g as bf16 into bufG (sEnd/sProd dead then)
  scan_passA<<<(BATCH * DI * NC) / 256, blk, 0, stream>>>(
      bufX, bufU, bufXD, dtb, alog, sEnd, sProd);
  scan_passB<<<(BATCH * DI * DSTATE) / 256, blk, 0, stream>>>(sEnd, sProd,
                                                              sInit);
  scan_passC<<<(BATCH * DI * NC) / 256, blk, 0, stream>>>(
      bufX, bufU, bufZ, bufXD, dtb, alog, Dv, sInit, bufG);
  // 7. out = g @ ow^T   (convert ow into sInit region, dead after passC)
  cvt_bf16_kernel<<<(int)(WN / 8 / 256), blk, 0, stream>>>(ow, owb,
                                                           (int)(WN / 8));
  gemm_bf16<<<dim3(DM / 128, M / 128), blk, 0, stream>>>(bufG, owb, out, DI,
                                                         DI, DI, DM);
}

// Round 11
// 256.053 us; speedup vs baseline: 6.3968x; 1.3370x over previous
//
#include <hip/hip_runtime.h>
#include <cstddef>
#include <cmath>
#include <type_traits>

#define BATCH 2
#define LSEQ 2048
#define DM 1024
#define DSTATE 16
#define DI 2048
#define DTR 64
#define XDR 96   // DTR + 2*DSTATE
#define NC 32    // scan chunks
#define TC 64    // timesteps per chunk (NC*TC == LSEQ)
#define PN (4096 * 96)  // per-z x_dbl partial size

using f32x4 = __attribute__((ext_vector_type(4))) float;
using bf16x8 = __attribute__((ext_vector_type(8))) short;
typedef unsigned short ushort_t;

__device__ __forceinline__ unsigned short f2bf(float f) {
  union { float f; unsigned int u; } c; c.f = f;
  unsigned int u = c.u;
  return (unsigned short)((u + 0x7FFFu + ((u >> 16) & 1u)) >> 16);  // RNE
}
__device__ __forceinline__ float bf2f(unsigned short h) {
  union { unsigned int u; float f; } c; c.u = ((unsigned int)h) << 16;
  return c.f;
}
__device__ __forceinline__ unsigned int pack2(float a, float b) {
  return (unsigned int)f2bf(a) | ((unsigned int)f2bf(b) << 16);
}

__device__ __forceinline__ void gl_lds16(const void* g, void* l) {
  __builtin_amdgcn_global_load_lds(
      (const __attribute__((address_space(1))) void*)g,
      (__attribute__((address_space(3))) void*)l, 16, 0, 0);
}

// ---------------------------------------------------------------------------
// f32 -> bf16 conversion, 8 elems/thread (exact-size grids).
// ---------------------------------------------------------------------------
__global__ __launch_bounds__(256) void cvt_bf16_kernel(
    const float* __restrict__ s, unsigned short* __restrict__ d, int n8) {
  int i = blockIdx.x * 256 + threadIdx.x;
  if (i >= n8) return;
  const float4* sp = reinterpret_cast<const float4*>(s) + (size_t)i * 2;
  float4 a = sp[0], b = sp[1];
  uint4 v = make_uint4(pack2(a.x, a.y), pack2(a.z, a.w), pack2(b.x, b.y),
                       pack2(b.z, b.w));
  *(reinterpret_cast<uint4*>(d) + i) = v;
}

// ---------------------------------------------------------------------------
// NT GEMM, bf16 in, f32 or bf16 out: C[m,n] = sum_k A[m*lda+k]*B[n*ldb+k].
// BM=BN=128, BK=64, 4 waves (2x2), 64x64/wave.  global_load_lds staging with
// pre-swizzled source slots (slot ^= row&7) + matching XOR on ds_read.
// XCD-aware bijective block swizzle (requires nwg % 8 == 0).
// Requires M%128==0, N%128==0, K%64==0.
// ---------------------------------------------------------------------------
template <typename OutT>
__global__ __launch_bounds__(256) void gemm_bf16_t(
    const unsigned short* __restrict__ A, const unsigned short* __restrict__ B,
    OutT* __restrict__ C, int K, int lda, int ldb, int ldc) {
  __shared__ __align__(16) unsigned short As[128][64];
  __shared__ __align__(16) unsigned short Bs[128][64];

  const int tid = threadIdx.x;
  const int lane = tid & 63;
  const int w = tid >> 6;

  const int gx = gridDim.x;
  const int nwg = gx * gridDim.y;
  const int id = blockIdx.y * gx + blockIdx.x;
  const int cpx = nwg >> 3;
  const int lt = (id & 7) * cpx + (id >> 3);
  const size_t m0 = (size_t)(lt / gx) * 128;
  const size_t n0 = (size_t)(lt % gx) * 128;

  const int rsub = lane >> 3;
  const int sslot = (lane & 7) ^ rsub;
  const unsigned short* Ab = A + m0 * lda + (size_t)rsub * lda + sslot * 8;
  const unsigned short* Bb = B + n0 * ldb + (size_t)rsub * ldb + sslot * 8;

  f32x4 acc[4][4] = {};

  const int fr = lane & 15;
  const int q = lane >> 4;
  const int f7 = fr & 7;

  for (int k0 = 0; k0 < K; k0 += 64) {
#pragma unroll
    for (int i = 0; i < 4; ++i) {
      const int r0 = w * 32 + i * 8;
      gl_lds16(Ab + (size_t)r0 * lda + k0, &As[r0][0]);
      gl_lds16(Bb + (size_t)r0 * ldb + k0, &Bs[r0][0]);
    }
    __syncthreads();

    bf16x8 af[4][2], bf_[4][2];
#pragma unroll
    for (int i = 0; i < 4; ++i) {
#pragma unroll
      for (int kk = 0; kk < 2; ++kk) {
        const int sA = (((kk * 4 + q) ^ f7) << 3);
        af[i][kk] = *reinterpret_cast<const bf16x8*>(
            &As[(w >> 1) * 64 + i * 16 + fr][sA]);
        bf_[i][kk] = *reinterpret_cast<const bf16x8*>(
            &Bs[(w & 1) * 64 + i * 16 + fr][sA]);
      }
    }
#pragma unroll
    for (int kk = 0; kk < 2; ++kk)
#pragma unroll
      for (int i = 0; i < 4; ++i)
#pragma unroll
        for (int j = 0; j < 4; ++j)
          acc[i][j] = __builtin_amdgcn_mfma_f32_16x16x32_bf16(
              af[i][kk], bf_[j][kk], acc[i][j], 0, 0, 0);
    __syncthreads();
  }

  const int crb = q * 4;
#pragma unroll
  for (int i = 0; i < 4; ++i) {
    size_t row = m0 + (w >> 1) * 64 + i * 16 + crb;
#pragma unroll
    for (int j = 0; j < 4; ++j) {
      size_t col = n0 + (w & 1) * 64 + j * 16 + fr;
#pragma unroll
      for (int r = 0; r < 4; ++r) {
        if constexpr (std::is_same_v<OutT, unsigned short>)
          C[(row + r) * ldc + col] = f2bf(acc[i][j][r]);
        else
          C[(row + r) * ldc + col] = acc[i][j][r];
      }
    }
  }
}

// ---------------------------------------------------------------------------
// Skinny x_dbl GEMM: P[z][m][c] = sum_{k in z-chunk} u[m][k]*xpw[c][k].
// BM=128, N=96, split-K x4 (blockIdx.y = z, K-chunk = 512).
// Same staging/swizzle scheme; 4 waves (2x2), wave tile 64x48.
// ---------------------------------------------------------------------------
__global__ __launch_bounds__(256) void gemm_xdbl(
    const unsigned short* __restrict__ A,  // u bf16 [4096][2048]
    const unsigned short* __restrict__ B,  // xpw bf16 [96][2048]
    float* __restrict__ P) {               // partials [4][4096][96]
  __shared__ __align__(16) unsigned short As[128][64];
  __shared__ __align__(16) unsigned short Bs[96][64];

  const int tid = threadIdx.x;
  const int lane = tid & 63;
  const int w = tid >> 6;
  const size_t m0 = (size_t)blockIdx.x * 128;
  const int k0base = blockIdx.y * 512;

  const int rsub = lane >> 3;
  const int sslot = (lane & 7) ^ rsub;
  const unsigned short* Ab = A + m0 * DI + (size_t)rsub * DI + sslot * 8;
  const unsigned short* Bb = B + (size_t)rsub * DI + sslot * 8;

  f32x4 acc[4][3] = {};

  const int fr = lane & 15;
  const int q = lane >> 4;
  const int f7 = fr & 7;

  for (int ks = 0; ks < 8; ++ks) {
    const int k0 = k0base + ks * 64;
#pragma unroll
    for (int i = 0; i < 4; ++i) {
      const int r0 = w * 32 + i * 8;
      gl_lds16(Ab + (size_t)r0 * DI + k0, &As[r0][0]);
    }
#pragma unroll
    for (int i = 0; i < 3; ++i) {
      const int r0 = w * 24 + i * 8;
      gl_lds16(Bb + (size_t)r0 * DI + k0, &Bs[r0][0]);
    }
    __syncthreads();

    bf16x8 af[4][2], bf_[3][2];
#pragma unroll
    for (int kk = 0; kk < 2; ++kk) {
      const int sA = (((kk * 4 + q) ^ f7) << 3);
#pragma unroll
      for (int i = 0; i < 4; ++i)
        af[i][kk] = *reinterpret_cast<const bf16x8*>(
            &As[(w >> 1) * 64 + i * 16 + fr][sA]);
#pragma unroll
      for (int j = 0; j < 3; ++j)
        bf_[j][kk] = *reinterpret_cast<const bf16x8*>(
            &Bs[(w & 1) * 48 + j * 16 + fr][sA]);
    }
#pragma unroll
    for (int kk = 0; kk < 2; ++kk)
#pragma unroll
      for (int i = 0; i < 4; ++i)
#pragma unroll
        for (int j = 0; j < 3; ++j)
          acc[i][j] = __builtin_amdgcn_mfma_f32_16x16x32_bf16(
              af[i][kk], bf_[j][kk], acc[i][j], 0, 0, 0);
    __syncthreads();
  }

  float* Pz = P + (size_t)blockIdx.y * PN;
  const int crb = q * 4;
#pragma unroll
  for (int i = 0; i < 4; ++i) {
    size_t row = m0 + (w >> 1) * 64 + i * 16 + crb;
#pragma unroll
    for (int j = 0; j < 3; ++j) {
      int col = (w & 1) * 48 + j * 16 + fr;
#pragma unroll
      for (int r = 0; r < 4; ++r) Pz[(row + r) * XDR + col] = acc[i][j][r];
    }
  }
}

// reduce split-K partials; emit dt as bf16 (cols 0..63) and compact B/C f32.
__global__ __launch_bounds__(256) void reduce4x_kernel(
    const float* __restrict__ P, unsigned short* __restrict__ dtB,
    float* __restrict__ BC) {
  int i = blockIdx.x * 256 + threadIdx.x;  // < 4096*96
  int row = i / XDR, col = i - row * XDR;
  float s = (P[i] + P[PN + i]) + (P[2 * PN + i] + P[3 * PN + i]);
  if (col < 64)
    dtB[row * 64 + col] = f2bf(s);
  else
    BC[row * 32 + (col - 64)] = s;
}

// ---------------------------------------------------------------------------
// Depthwise causal conv (D_CONV=4) + bias + SiLU; f32 in, bf16 out.
// ---------------------------------------------------------------------------
__global__ __launch_bounds__(256) void conv_silu_kernel(
    const float* __restrict__ x, const float* __restrict__ w,
    const float* __restrict__ cb, unsigned short* __restrict__ out) {
  int idx = blockIdx.x * 256 + threadIdx.x;
  int e4 = idx % (DI / 4);
  int bl = idx / (DI / 4);
  int l = bl % LSEQ;
  int e = e4 * 4;

  const float4* cw = reinterpret_cast<const float4*>(w);
  float4 w0 = cw[e], w1 = cw[e + 1], w2 = cw[e + 2], w3 = cw[e + 3];
  float4 acc = *reinterpret_cast<const float4*>(&cb[e]);

#define TAPK(K, COMP)                                                       \
  {                                                                         \
    int ls = l - 3 + (K);                                                   \
    if (ls >= 0) {                                                          \
      float4 xv = *reinterpret_cast<const float4*>(                         \
          &x[((size_t)(bl) - 3 + (K)) * DI + e]);                           \
      acc.x = fmaf(xv.x, w0.COMP, acc.x);                                   \
      acc.y = fmaf(xv.y, w1.COMP, acc.y);                                   \
      acc.z = fmaf(xv.z, w2.COMP, acc.z);                                   \
      acc.w = fmaf(xv.w, w3.COMP, acc.w);                                   \
    }                                                                       \
  }
  TAPK(0, x)
  TAPK(1, y)
  TAPK(2, z)
  TAPK(3, w)
#undef TAPK

  acc.x = acc.x / (1.f + expf(-acc.x));
  acc.y = acc.y / (1.f + expf(-acc.y));
  acc.z = acc.z / (1.f + expf(-acc.z));
  acc.w = acc.w / (1.f + expf(-acc.w));
  *reinterpret_cast<uint2*>(&out[(size_t)bl * DI + e]) =
      make_uint2(pack2(acc.x, acc.y), pack2(acc.z, acc.w));
}

// ---------------------------------------------------------------------------
// Chunked selective scan, 16 states/thread.  u,z bf16; B/C from compact
// [BL][32] f32 buffer (B = +0..15, C = +16..31).
// ---------------------------------------------------------------------------
__device__ __forceinline__ float softplus_fast(float x) {
  float ex = __expf(x);
  return (x > 20.f) ? x : __logf(1.f + ex);
}

__global__ __launch_bounds__(256) void scan_passA(
    const float* __restrict__ draw, const unsigned short* __restrict__ u,
    const float* __restrict__ bc, const float* __restrict__ dtb,
    const float* __restrict__ A_log, float* __restrict__ sEnd,
    float* __restrict__ sProd) {
  int g = blockIdx.x * 256 + threadIdx.x;  // B*E*NC = 131072
  int e = g & (DI - 1);
  int c = (g >> 11) & (NC - 1);
  int b = g >> 16;

  float nA[DSTATE];
#pragma unroll
  for (int n = 0; n < DSTATE; ++n) nA[n] = -__expf(A_log[e * DSTATE + n]);
  const float bias = dtb[e];

  size_t off = ((size_t)b * LSEQ + c * TC) * DI + e;
  size_t boff = ((size_t)b * LSEQ + c * TC) * 32;

  float s[DSTATE], P[DSTATE];
#pragma unroll
  for (int n = 0; n < DSTATE; ++n) { s[n] = 0.f; P[n] = 1.f; }

  float dr = draw[off];
  float ut = bf2f(u[off]);
  float4 B0 = *reinterpret_cast<const float4*>(&bc[boff]);
  float4 B1 = *reinterpret_cast<const float4*>(&bc[boff + 4]);
  float4 B2 = *reinterpret_cast<const float4*>(&bc[boff + 8]);
  float4 B3 = *reinterpret_cast<const float4*>(&bc[boff + 12]);

  for (int t = 0; t < TC; ++t) {
    float dr_n = 0.f, ut_n = 0.f;
    float4 B0n = {}, B1n = {}, B2n = {}, B3n = {};
    if (t + 1 < TC) {
      dr_n = draw[off + DI];
      ut_n = bf2f(u[off + DI]);
      B0n = *reinterpret_cast<const float4*>(&bc[boff + 32]);
      B1n = *reinterpret_cast<const float4*>(&bc[boff + 36]);
      B2n = *reinterpret_cast<const float4*>(&bc[boff + 40]);
      B3n = *reinterpret_cast<const float4*>(&bc[boff + 44]);
    }

    float d = softplus_fast(dr + bias);
    float db = d * ut;
    float Bv[DSTATE] = {B0.x, B0.y, B0.z, B0.w, B1.x, B1.y, B1.z, B1.w,
                        B2.x, B2.y, B2.z, B2.w, B3.x, B3.y, B3.z, B3.w};
#pragma unroll
    for (int n = 0; n < DSTATE; ++n) {
      float dA = __expf(d * nA[n]);
      s[n] = fmaf(s[n], dA, db * Bv[n]);
      P[n] *= dA;
    }
    off += DI;
    boff += 32;
    dr = dr_n; ut = ut_n;
    B0 = B0n; B1 = B1n; B2 = B2n; B3 = B3n;
  }

  size_t o = (((size_t)b * NC + c) * DI + e) * DSTATE;
  float4* se = reinterpret_cast<float4*>(&sEnd[o]);
  float4* sp = reinterpret_cast<float4*>(&sProd[o]);
  se[0] = make_float4(s[0], s[1], s[2], s[3]);
  se[1] = make_float4(s[4], s[5], s[6], s[7]);
  se[2] = make_float4(s[8], s[9], s[10], s[11]);
  se[3] = make_float4(s[12], s[13], s[14], s[15]);
  sp[0] = make_float4(P[0], P[1], P[2], P[3]);
  sp[1] = make_float4(P[4], P[5], P[6], P[7]);
  sp[2] = make_float4(P[8], P[9], P[10], P[11]);
  sp[3] = make_float4(P[12], P[13], P[14], P[15]);
}

__global__ __launch_bounds__(256) void scan_passB(
    const float* __restrict__ sEnd, const float* __restrict__ sProd,
    float* __restrict__ sInit) {
  int g = blockIdx.x * 256 + threadIdx.x;  // 65,536
  int n = g & 15;
  int e = (g >> 4) & (DI - 1);
  int b = g >> 15;
  float s = 0.f;
  for (int c = 0; c < NC; ++c) {
    size_t o = (((size_t)b * NC + c) * DI + e) * DSTATE + n;
    sInit[o] = s;
    s = fmaf(s, sProd[o], sEnd[o]);
  }
}

__global__ __launch_bounds__(256) void scan_passC(
    const float* __restrict__ draw, const unsigned short* __restrict__ u,
    const unsigned short* __restrict__ z, const float* __restrict__ bc,
    const float* __restrict__ dtb, const float* __restrict__ A_log,
    const float* __restrict__ Dv, const float* __restrict__ sInit,
    unsigned short* __restrict__ gOut) {
  int g = blockIdx.x * 256 + threadIdx.x;  // 131072
  int e = g & (DI - 1);
  int c = (g >> 11) & (NC - 1);
  int b = g >> 16;

  float nA[DSTATE];
#pragma unroll
  for (int n = 0; n < DSTATE; ++n) nA[n] = -__expf(A_log[e * DSTATE + n]);
  const float bias = dtb[e];
  const float Dval = Dv[e];

  size_t off = ((size_t)b * LSEQ + c * TC) * DI + e;
  size_t boff = ((size_t)b * LSEQ + c * TC) * 32;

  float s[DSTATE];
  {
    size_t o = (((size_t)b * NC + c) * DI + e) * DSTATE;
    const float4* si = reinterpret_cast<const float4*>(&sInit[o]);
    float4 s0 = si[0], s1 = si[1], s2 = si[2], s3 = si[3];
    s[0] = s0.x; s[1] = s0.y; s[2] = s0.z; s[3] = s0.w;
    s[4] = s1.x; s[5] = s1.y; s[6] = s1.z; s[7] = s1.w;
    s[8] = s2.x; s[9] = s2.y; s[10] = s2.z; s[11] = s2.w;
    s[12] = s3.x; s[13] = s3.y; s[14] = s3.z; s[15] = s3.w;
  }

  float dr = draw[off];
  float ut = bf2f(u[off]);
  float zt = bf2f(z[off]);
  float4 B0 = *reinterpret_cast<const float4*>(&bc[boff]);
  float4 B1 = *reinterpret_cast<const float4*>(&bc[boff + 4]);
  float4 B2 = *reinterpret_cast<const float4*>(&bc[boff + 8]);
  float4 B3 = *reinterpret_cast<const float4*>(&bc[boff + 12]);
  float4 C0 = *reinterpret_cast<const float4*>(&bc[boff + 16]);
  float4 C1 = *reinterpret_cast<const float4*>(&bc[boff + 20]);
  float4 C2 = *reinterpret_cast<const float4*>(&bc[boff + 24]);
  float4 C3 = *reinterpret_cast<const float4*>(&bc[boff + 28]);

  for (int t = 0; t < TC; ++t) {
    float dr_n = 0.f, ut_n = 0.f, zt_n = 0.f;
    float4 B0n = {}, B1n = {}, B2n = {}, B3n = {};
    float4 C0n = {}, C1n = {}, C2n = {}, C3n = {};
    if (t + 1 < TC) {
      dr_n = draw[off + DI];
      ut_n = bf2f(u[off + DI]);
      zt_n = bf2f(z[off + DI]);
      B0n = *reinterpret_cast<const float4*>(&bc[boff + 32]);
      B1n = *reinterpret_cast<const float4*>(&bc[boff + 36]);
      B2n = *reinterpret_cast<const float4*>(&bc[boff + 40]);
      B3n = *reinterpret_cast<const float4*>(&bc[boff + 44]);
      C0n = *reinterpret_cast<const float4*>(&bc[boff + 48]);
      C1n = *reinterpret_cast<const float4*>(&bc[boff + 52]);
      C2n = *reinterpret_cast<const float4*>(&bc[boff + 56]);
      C3n = *reinterpret_cast<const float4*>(&bc[boff + 60]);
    }

    float d = softplus_fast(dr + bias);
    float db = d * ut;
    float Bv[DSTATE] = {B0.x, B0.y, B0.z, B0.w, B1.x, B1.y, B1.z, B1.w,
                        B2.x, B2.y, B2.z, B2.w, B3.x, B3.y, B3.z, B3.w};
    float Cv[DSTATE] = {C0.x, C0.y, C0.z, C0.w, C1.x, C1.y, C1.z, C1.w,
                        C2.x, C2.y, C2.z, C2.w, C3.x, C3.y, C3.z, C3.w};
    float y = 0.f;
#pragma unroll
    for (int n = 0; n < DSTATE; ++n) {
      float dA = __expf(d * nA[n]);
      s[n] = fmaf(s[n], dA, db * Bv[n]);
      y = fmaf(s[n], Cv[n], y);
    }
    float gate = zt / (1.f + __expf(-zt));
    gOut[off] = f2bf((y + Dval * ut) * gate);

    off += DI;
    boff += 32;
    dr = dr_n; ut = ut_n; zt = zt_n;
    B0 = B0n; B1 = B1n; B2 = B2n; B3 = B3n;
    C0 = C0n; C1 = C1n; C2 = C2n; C3 = C3n;
  }
}

// ---------------------------------------------------------------------------
extern "C" void kernel_launch(void* const* d_in, const int* in_sizes, int n_in,
                              void* d_out, int out_size, void* d_ws,
                              size_t ws_size, hipStream_t stream) {
  const float* hs = (const float*)d_in[0];
  const float* in2 = (const float*)d_in[1];
  const float* w1 = (const float*)d_in[2];
  const float* w2 = (const float*)d_in[3];
  const float* cw = (const float*)d_in[4];
  const float* cb = (const float*)d_in[5];
  const float* xpw = (const float*)d_in[6];
  const float* dtw = (const float*)d_in[7];
  const float* dtb = (const float*)d_in[8];
  const float* alog = (const float*)d_in[9];
  const float* Dv = (const float*)d_in[10];
  const float* ow = (const float*)d_in[11];
  float* out = (float*)d_out;

  const size_t BLE = (size_t)BATCH * LSEQ * DI;   // 8,388,608
  const size_t BLM = (size_t)BATCH * LSEQ * DM;   // 4,194,304
  const size_t WN = (size_t)DI * DM;              // 2,097,152
  const size_t SC = (size_t)BATCH * NC * DI * DSTATE;  // 2,097,152

  // Regions (floats):
  float* W = (float*)d_ws;
  float* bufX = W;                       // BLE: x_pre -> delta_raw (f32)
  float* M2 = W + BLE;                   // BLE/2: hsb -> zb (bf16)
  float* M3 = M2 + BLE / 2;              // BLE/2: in2b -> ub (bf16)
  float* M4 = M3 + BLE / 2;              // BLE/2: wb1|wb2 -> xdblP|xpwB|dtB|dtwB -> bufG
  float* sEnd = M4 + BLE / 2;            // SC
  float* sProd = sEnd + SC;              // SC
  float* sInit = sProd + SC;             // SC; -> owb after passC
  float* BC = sInit + SC;                // 4096*32 = 131,072

  unsigned short* hsb = (unsigned short*)M2;
  unsigned short* zb = (unsigned short*)M2;
  unsigned short* in2b = (unsigned short*)M3;
  unsigned short* ub = (unsigned short*)M3;
  unsigned short* wb1 = (unsigned short*)M4;
  unsigned short* wb2 = wb1 + WN;
  float* xdblP = M4;                                        // 4*PN floats
  unsigned short* xpwB = (unsigned short*)(M4 + 4 * PN);    // 96*2048
  unsigned short* dtB = (unsigned short*)(M4 + 4 * PN + 98304 + 16);
  unsigned short* dtwB = (unsigned short*)(M4 + 4 * PN + 98304 + 131072 + 32);
  unsigned short* bufG = (unsigned short*)M4;
  unsigned short* owb = (unsigned short*)sInit;

  const int M = BATCH * LSEQ;  // 4096
  dim3 blk(256);

  // 0. convert GEMM operands to bf16
  cvt_bf16_kernel<<<(int)(BLM / 8 / 256), blk, 0, stream>>>(hs, hsb,
                                                            (int)(BLM / 8));
  cvt_bf16_kernel<<<(int)(BLM / 8 / 256), blk, 0, stream>>>(in2, in2b,
                                                            (int)(BLM / 8));
  cvt_bf16_kernel<<<(int)(WN / 8 / 256), blk, 0, stream>>>(w1, wb1,
                                                           (int)(WN / 8));
  cvt_bf16_kernel<<<(int)(WN / 8 / 256), blk, 0, stream>>>(w2, wb2,
                                                           (int)(WN / 8));
  // 1. x_pre = hs @ w1^T  (f32 out)
  gemm_bf16_t<float><<<dim3(DI / 128, M / 128), blk, 0, stream>>>(
      hsb, wb1, bufX, DM, DM, DM, DI);
  // 2. z = in2 @ w2^T  (bf16 out; hsb dead)
  gemm_bf16_t<unsigned short><<<dim3(DI / 128, M / 128), blk, 0, stream>>>(
      in2b, wb2, zb, DM, DM, DM, DI);
  // 3. u = silu(conv(x_pre) + cb)  (bf16 out; in2b dead)
  conv_silu_kernel<<<(M * (DI / 4)) / 256, blk, 0, stream>>>(bufX, cw, cb, ub);
  // 3b. convert xpw, dtw (wb1/wb2 dead)
  cvt_bf16_kernel<<<96, blk, 0, stream>>>(xpw, xpwB, XDR * DI / 8);
  cvt_bf16_kernel<<<64, blk, 0, stream>>>(dtw, dtwB, DI * DTR / 8);
  // 4. x_dbl partials = u @ xpw^T (split-K x4, MFMA) + reduce
  gemm_xdbl<<<dim3(M / 128, 4), blk, 0, stream>>>(ub, xpwB, xdblP);
  reduce4x_kernel<<<(M * XDR) / 256, blk, 0, stream>>>(xdblP, dtB, BC);
  // 5. delta_raw = dt @ dtw^T  (MFMA, K=64, f32 out into bufX)
  gemm_bf16_t<float><<<dim3(DI / 128, M / 128), blk, 0, stream>>>(
      dtB, dtwB, bufX, DTR, DTR, DTR, DI);
  // 6. chunked scan; passC emits g as bf16 into bufG
  scan_passA<<<(BATCH * DI * NC) / 256, blk, 0, stream>>>(bufX, ub, BC, dtb,
                                                          alog, sEnd, sProd);
  scan_passB<<<(BATCH * DI * DSTATE) / 256, blk, 0, stream>>>(sEnd, sProd,
                                                              sInit);
  scan_passC<<<(BATCH * DI * NC) / 256, blk, 0, stream>>>(
      bufX, ub, zb, BC, dtb, alog, Dv, sInit, bufG);
  // 7. out = g @ ow^T  (owb into sInit region, dead after passC)
  cvt_bf16_kernel<<<(int)(WN / 8 / 256), blk, 0, stream>>>(ow, owb,
                                                           (int)(WN / 8));
  gemm_bf16_t<float><<<dim3(DM / 128, M / 128), blk, 0, stream>>>(
      bufG, owb, out, DI, DI, DI, DM);
}

// Round 12
// 249.342 us; speedup vs baseline: 6.5690x; 1.0269x over previous
//
#include <hip/hip_runtime.h>
#include <cstddef>
#include <cmath>
#include <type_traits>

#define BATCH 2
#define LSEQ 2048
#define DM 1024
#define DSTATE 16
#define DI 2048
#define DTR 64
#define XDR 96   // DTR + 2*DSTATE
#define NC 64    // scan chunks
#define TC 32    // timesteps per chunk (NC*TC == LSEQ)
#define PN (4096 * 96)  // per-z x_dbl partial size

using f32x4 = __attribute__((ext_vector_type(4))) float;
using bf16x8 = __attribute__((ext_vector_type(8))) short;

__device__ __forceinline__ unsigned short f2bf(float f) {
  union { float f; unsigned int u; } c; c.f = f;
  unsigned int u = c.u;
  return (unsigned short)((u + 0x7FFFu + ((u >> 16) & 1u)) >> 16);  // RNE
}
__device__ __forceinline__ float bf2f(unsigned short h) {
  union { unsigned int u; float f; } c; c.u = ((unsigned int)h) << 16;
  return c.f;
}
__device__ __forceinline__ unsigned int pack2(float a, float b) {
  return (unsigned int)f2bf(a) | ((unsigned int)f2bf(b) << 16);
}

__device__ __forceinline__ void gl_lds16(const void* g, void* l) {
  __builtin_amdgcn_global_load_lds(
      (const __attribute__((address_space(1))) void*)g,
      (__attribute__((address_space(3))) void*)l, 16, 0, 0);
}

__device__ __forceinline__ float softplus_fast(float x) {
  float ex = __expf(x);
  return (x > 20.f) ? x : __logf(1.f + ex);
}

// ---------------------------------------------------------------------------
// f32 -> bf16 conversion, 8 elems/thread (exact-size grids).
// ---------------------------------------------------------------------------
__global__ __launch_bounds__(256) void cvt_bf16_kernel(
    const float* __restrict__ s, unsigned short* __restrict__ d, int n8) {
  int i = blockIdx.x * 256 + threadIdx.x;
  if (i >= n8) return;
  const float4* sp = reinterpret_cast<const float4*>(s) + (size_t)i * 2;
  float4 a = sp[0], b = sp[1];
  uint4 v = make_uint4(pack2(a.x, a.y), pack2(a.z, a.w), pack2(b.x, b.y),
                       pack2(b.z, b.w));
  *(reinterpret_cast<uint4*>(d) + i) = v;
}

// ---------------------------------------------------------------------------
// NT GEMM, bf16 in, f32 or bf16 out: C[m,n] = sum_k A[m*lda+k]*B[n*ldb+k].
// BM=BN=128, BK=64, 4 waves (2x2), 64x64/wave.  global_load_lds staging with
// pre-swizzled source slots (slot ^= row&7) + matching XOR on ds_read.
// XCD-aware bijective block swizzle (requires nwg % 8 == 0).
// ---------------------------------------------------------------------------
template <typename OutT>
__global__ __launch_bounds__(256) void gemm_bf16_t(
    const unsigned short* __restrict__ A, const unsigned short* __restrict__ B,
    OutT* __restrict__ C, int K, int lda, int ldb, int ldc) {
  __shared__ __align__(16) unsigned short As[128][64];
  __shared__ __align__(16) unsigned short Bs[128][64];

  const int tid = threadIdx.x;
  const int lane = tid & 63;
  const int w = tid >> 6;

  const int gx = gridDim.x;
  const int nwg = gx * gridDim.y;
  const int id = blockIdx.y * gx + blockIdx.x;
  const int cpx = nwg >> 3;
  const int lt = (id & 7) * cpx + (id >> 3);
  const size_t m0 = (size_t)(lt / gx) * 128;
  const size_t n0 = (size_t)(lt % gx) * 128;

  const int rsub = lane >> 3;
  const int sslot = (lane & 7) ^ rsub;
  const unsigned short* Ab = A + m0 * lda + (size_t)rsub * lda + sslot * 8;
  const unsigned short* Bb = B + n0 * ldb + (size_t)rsub * ldb + sslot * 8;

  f32x4 acc[4][4] = {};

  const int fr = lane & 15;
  const int q = lane >> 4;
  const int f7 = fr & 7;

  for (int k0 = 0; k0 < K; k0 += 64) {
#pragma unroll
    for (int i = 0; i < 4; ++i) {
      const int r0 = w * 32 + i * 8;
      gl_lds16(Ab + (size_t)r0 * lda + k0, &As[r0][0]);
      gl_lds16(Bb + (size_t)r0 * ldb + k0, &Bs[r0][0]);
    }
    __syncthreads();

    bf16x8 af[4][2], bf_[4][2];
#pragma unroll
    for (int i = 0; i < 4; ++i) {
#pragma unroll
      for (int kk = 0; kk < 2; ++kk) {
        const int sA = (((kk * 4 + q) ^ f7) << 3);
        af[i][kk] = *reinterpret_cast<const bf16x8*>(
            &As[(w >> 1) * 64 + i * 16 + fr][sA]);
        bf_[i][kk] = *reinterpret_cast<const bf16x8*>(
            &Bs[(w & 1) * 64 + i * 16 + fr][sA]);
      }
    }
#pragma unroll
    for (int kk = 0; kk < 2; ++kk)
#pragma unroll
      for (int i = 0; i < 4; ++i)
#pragma unroll
        for (int j = 0; j < 4; ++j)
          acc[i][j] = __builtin_amdgcn_mfma_f32_16x16x32_bf16(
              af[i][kk], bf_[j][kk], acc[i][j], 0, 0, 0);
    __syncthreads();
  }

  const int crb = q * 4;
#pragma unroll
  for (int i = 0; i < 4; ++i) {
    size_t row = m0 + (w >> 1) * 64 + i * 16 + crb;
#pragma unroll
    for (int j = 0; j < 4; ++j) {
      size_t col = n0 + (w & 1) * 64 + j * 16 + fr;
#pragma unroll
      for (int r = 0; r < 4; ++r) {
        if constexpr (std::is_same_v<OutT, unsigned short>)
          C[(row + r) * ldc + col] = f2bf(acc[i][j][r]);
        else
          C[(row + r) * ldc + col] = acc[i][j][r];
      }
    }
  }
}

// ---------------------------------------------------------------------------
// Delta GEMM with fused bias+softplus epilogue, bf16 out:
// d[m,e] = softplus(sum_r dt[m,r]*dtw[e,r] + dtb[e]).  Same structure.
// ---------------------------------------------------------------------------
__global__ __launch_bounds__(256) void gemm_delta(
    const unsigned short* __restrict__ A, const unsigned short* __restrict__ B,
    const float* __restrict__ bias, unsigned short* __restrict__ C, int K,
    int lda, int ldb, int ldc) {
  __shared__ __align__(16) unsigned short As[128][64];
  __shared__ __align__(16) unsigned short Bs[128][64];

  const int tid = threadIdx.x;
  const int lane = tid & 63;
  const int w = tid >> 6;

  const int gx = gridDim.x;
  const int nwg = gx * gridDim.y;
  const int id = blockIdx.y * gx + blockIdx.x;
  const int cpx = nwg >> 3;
  const int lt = (id & 7) * cpx + (id >> 3);
  const size_t m0 = (size_t)(lt / gx) * 128;
  const size_t n0 = (size_t)(lt % gx) * 128;

  const int rsub = lane >> 3;
  const int sslot = (lane & 7) ^ rsub;
  const unsigned short* Ab = A + m0 * lda + (size_t)rsub * lda + sslot * 8;
  const unsigned short* Bb = B + n0 * ldb + (size_t)rsub * ldb + sslot * 8;

  f32x4 acc[4][4] = {};

  const int fr = lane & 15;
  const int q = lane >> 4;
  const int f7 = fr & 7;

  for (int k0 = 0; k0 < K; k0 += 64) {
#pragma unroll
    for (int i = 0; i < 4; ++i) {
      const int r0 = w * 32 + i * 8;
      gl_lds16(Ab + (size_t)r0 * lda + k0, &As[r0][0]);
      gl_lds16(Bb + (size_t)r0 * ldb + k0, &Bs[r0][0]);
    }
    __syncthreads();

    bf16x8 af[4][2], bf_[4][2];
#pragma unroll
    for (int i = 0; i < 4; ++i) {
#pragma unroll
      for (int kk = 0; kk < 2; ++kk) {
        const int sA = (((kk * 4 + q) ^ f7) << 3);
        af[i][kk] = *reinterpret_cast<const bf16x8*>(
            &As[(w >> 1) * 64 + i * 16 + fr][sA]);
        bf_[i][kk] = *reinterpret_cast<const bf16x8*>(
            &Bs[(w & 1) * 64 + i * 16 + fr][sA]);
      }
    }
#pragma unroll
    for (int kk = 0; kk < 2; ++kk)
#pragma unroll
      for (int i = 0; i < 4; ++i)
#pragma unroll
        for (int j = 0; j < 4; ++j)
          acc[i][j] = __builtin_amdgcn_mfma_f32_16x16x32_bf16(
              af[i][kk], bf_[j][kk], acc[i][j], 0, 0, 0);
    __syncthreads();
  }

  const int crb = q * 4;
#pragma unroll
  for (int i = 0; i < 4; ++i) {
    size_t row = m0 + (w >> 1) * 64 + i * 16 + crb;
#pragma unroll
    for (int j = 0; j < 4; ++j) {
      size_t col = n0 + (w & 1) * 64 + j * 16 + fr;
      float bv = bias[col];
#pragma unroll
      for (int r = 0; r < 4; ++r)
        C[(row + r) * ldc + col] = f2bf(softplus_fast(acc[i][j][r] + bv));
    }
  }
}

// ---------------------------------------------------------------------------
// Skinny x_dbl GEMM: P[z][m][c] = sum_{k in z-chunk} u[m][k]*xpw[c][k].
// ---------------------------------------------------------------------------
__global__ __launch_bounds__(256) void gemm_xdbl(
    const unsigned short* __restrict__ A,  // u bf16 [4096][2048]
    const unsigned short* __restrict__ B,  // xpw bf16 [96][2048]
    float* __restrict__ P) {               // partials [4][4096][96]
  __shared__ __align__(16) unsigned short As[128][64];
  __shared__ __align__(16) unsigned short Bs[96][64];

  const int tid = threadIdx.x;
  const int lane = tid & 63;
  const int w = tid >> 6;
  const size_t m0 = (size_t)blockIdx.x * 128;
  const int k0base = blockIdx.y * 512;

  const int rsub = lane >> 3;
  const int sslot = (lane & 7) ^ rsub;
  const unsigned short* Ab = A + m0 * DI + (size_t)rsub * DI + sslot * 8;
  const unsigned short* Bb = B + (size_t)rsub * DI + sslot * 8;

  f32x4 acc[4][3] = {};

  const int fr = lane & 15;
  const int q = lane >> 4;
  const int f7 = fr & 7;

  for (int ks = 0; ks < 8; ++ks) {
    const int k0 = k0base + ks * 64;
#pragma unroll
    for (int i = 0; i < 4; ++i) {
      const int r0 = w * 32 + i * 8;
      gl_lds16(Ab + (size_t)r0 * DI + k0, &As[r0][0]);
    }
#pragma unroll
    for (int i = 0; i < 3; ++i) {
      const int r0 = w * 24 + i * 8;
      gl_lds16(Bb + (size_t)r0 * DI + k0, &Bs[r0][0]);
    }
    __syncthreads();

    bf16x8 af[4][2], bf_[3][2];
#pragma unroll
    for (int kk = 0; kk < 2; ++kk) {
      const int sA = (((kk * 4 + q) ^ f7) << 3);
#pragma unroll
      for (int i = 0; i < 4; ++i)
        af[i][kk] = *reinterpret_cast<const bf16x8*>(
            &As[(w >> 1) * 64 + i * 16 + fr][sA]);
#pragma unroll
      for (int j = 0; j < 3; ++j)
        bf_[j][kk] = *reinterpret_cast<const bf16x8*>(
            &Bs[(w & 1) * 48 + j * 16 + fr][sA]);
    }
#pragma unroll
    for (int kk = 0; kk < 2; ++kk)
#pragma unroll
      for (int i = 0; i < 4; ++i)
#pragma unroll
        for (int j = 0; j < 3; ++j)
          acc[i][j] = __builtin_amdgcn_mfma_f32_16x16x32_bf16(
              af[i][kk], bf_[j][kk], acc[i][j], 0, 0, 0);
    __syncthreads();
  }

  float* Pz = P + (size_t)blockIdx.y * PN;
  const int crb = q * 4;
#pragma unroll
  for (int i = 0; i < 4; ++i) {
    size_t row = m0 + (w >> 1) * 64 + i * 16 + crb;
#pragma unroll
    for (int j = 0; j < 3; ++j) {
      int col = (w & 1) * 48 + j * 16 + fr;
#pragma unroll
      for (int r = 0; r < 4; ++r) Pz[(row + r) * XDR + col] = acc[i][j][r];
    }
  }
}

// reduce split-K partials; emit dt as bf16 (cols 0..63) and compact B/C f32.
__global__ __launch_bounds__(256) void reduce4x_kernel(
    const float* __restrict__ P, unsigned short* __restrict__ dtB,
    float* __restrict__ BC) {
  int i = blockIdx.x * 256 + threadIdx.x;  // < 4096*96
  int row = i / XDR, col = i - row * XDR;
  float s = (P[i] + P[PN + i]) + (P[2 * PN + i] + P[3 * PN + i]);
  if (col < 64)
    dtB[row * 64 + col] = f2bf(s);
  else
    BC[row * 32 + (col - 64)] = s;
}

// ---------------------------------------------------------------------------
// Depthwise causal conv (D_CONV=4) + bias + SiLU; f32 in, bf16 out.
// ---------------------------------------------------------------------------
__global__ __launch_bounds__(256) void conv_silu_kernel(
    const float* __restrict__ x, const float* __restrict__ w,
    const float* __restrict__ cb, unsigned short* __restrict__ out) {
  int idx = blockIdx.x * 256 + threadIdx.x;
  int e4 = idx % (DI / 4);
  int bl = idx / (DI / 4);
  int l = bl % LSEQ;
  int e = e4 * 4;

  const float4* cw = reinterpret_cast<const float4*>(w);
  float4 w0 = cw[e], w1 = cw[e + 1], w2 = cw[e + 2], w3 = cw[e + 3];
  float4 acc = *reinterpret_cast<const float4*>(&cb[e]);

#define TAPK(K, COMP)                                                       \
  {                                                                         \
    int ls = l - 3 + (K);                                                   \
    if (ls >= 0) {                                                          \
      float4 xv = *reinterpret_cast<const float4*>(                         \
          &x[((size_t)(bl) - 3 + (K)) * DI + e]);                           \
      acc.x = fmaf(xv.x, w0.COMP, acc.x);                                   \
      acc.y = fmaf(xv.y, w1.COMP, acc.y);                                   \
      acc.z = fmaf(xv.z, w2.COMP, acc.z);                                   \
      acc.w = fmaf(xv.w, w3.COMP, acc.w);                                   \
    }                                                                       \
  }
  TAPK(0, x)
  TAPK(1, y)
  TAPK(2, z)
  TAPK(3, w)
#undef TAPK

  acc.x = acc.x / (1.f + expf(-acc.x));
  acc.y = acc.y / (1.f + expf(-acc.y));
  acc.z = acc.z / (1.f + expf(-acc.z));
  acc.w = acc.w / (1.f + expf(-acc.w));
  *reinterpret_cast<uint2*>(&out[(size_t)bl * DI + e]) =
      make_uint2(pack2(acc.x, acc.y), pack2(acc.z, acc.w));
}

// ---------------------------------------------------------------------------
// Chunked selective scan, 16 states/thread.  d (pre-softplus'ed) bf16;
// u,z bf16; B/C from compact [BL][32] f32 buffer.
// dA[n] = exp(d*nA[n]); when nA[n] == (n+1)*nA[0] (true for this model's
// A_log = log(1..16)), computed as q^(n+1) with one exp.  Uniform runtime
// check falls back to the generic 16-exp path.
// ---------------------------------------------------------------------------
__global__ __launch_bounds__(256) void scan_passA(
    const unsigned short* __restrict__ dB, const unsigned short* __restrict__ u,
    const float* __restrict__ bc, const float* __restrict__ A_log,
    float* __restrict__ sEnd, float* __restrict__ sProd) {
  int g = blockIdx.x * 256 + threadIdx.x;  // B*E*NC = 262144
  int e = g & (DI - 1);
  int c = (g >> 11) & (NC - 1);
  int b = g >> 17;

  float nA[DSTATE];
#pragma unroll
  for (int n = 0; n < DSTATE; ++n) nA[n] = -__expf(A_log[e * DSTATE + n]);
  const float nA0 = nA[0];
  bool aok = true;
#pragma unroll
  for (int n = 1; n < DSTATE; ++n)
    aok = aok && (fabsf(nA[n] - (float)(n + 1) * nA0) <=
                  1e-4f * fabsf(nA[n]));

  size_t off = ((size_t)b * LSEQ + c * TC) * DI + e;
  size_t boff = ((size_t)b * LSEQ + c * TC) * 32;

  float s[DSTATE], P[DSTATE];
#pragma unroll
  for (int n = 0; n < DSTATE; ++n) { s[n] = 0.f; P[n] = 1.f; }

  float d = bf2f(dB[off]);
  float ut = bf2f(u[off]);
  float4 B0 = *reinterpret_cast<const float4*>(&bc[boff]);
  float4 B1 = *reinterpret_cast<const float4*>(&bc[boff + 4]);
  float4 B2 = *reinterpret_cast<const float4*>(&bc[boff + 8]);
  float4 B3 = *reinterpret_cast<const float4*>(&bc[boff + 12]);

  for (int t = 0; t < TC; ++t) {
    float d_n = 0.f, ut_n = 0.f;
    float4 B0n = {}, B1n = {}, B2n = {}, B3n = {};
    if (t + 1 < TC) {
      d_n = bf2f(dB[off + DI]);
      ut_n = bf2f(u[off + DI]);
      B0n = *reinterpret_cast<const float4*>(&bc[boff + 32]);
      B1n = *reinterpret_cast<const float4*>(&bc[boff + 36]);
      B2n = *reinterpret_cast<const float4*>(&bc[boff + 40]);
      B3n = *reinterpret_cast<const float4*>(&bc[boff + 44]);
    }

    float db = d * ut;
    float dA[DSTATE];
    if (aok) {
      float qq = __expf(d * nA0);
      dA[0] = qq;
#pragma unroll
      for (int n = 1; n < DSTATE; ++n) dA[n] = dA[n - 1] * qq;
    } else {
#pragma unroll
      for (int n = 0; n < DSTATE; ++n) dA[n] = __expf(d * nA[n]);
    }
    float Bv[DSTATE] = {B0.x, B0.y, B0.z, B0.w, B1.x, B1.y, B1.z, B1.w,
                        B2.x, B2.y, B2.z, B2.w, B3.x, B3.y, B3.z, B3.w};
#pragma unroll
    for (int n = 0; n < DSTATE; ++n) {
      s[n] = fmaf(s[n], dA[n], db * Bv[n]);
      P[n] *= dA[n];
    }
    off += DI;
    boff += 32;
    d = d_n; ut = ut_n;
    B0 = B0n; B1 = B1n; B2 = B2n; B3 = B3n;
  }

  size_t o = (((size_t)b * NC + c) * DI + e) * DSTATE;
  float4* se = reinterpret_cast<float4*>(&sEnd[o]);
  float4* sp = reinterpret_cast<float4*>(&sProd[o]);
  se[0] = make_float4(s[0], s[1], s[2], s[3]);
  se[1] = make_float4(s[4], s[5], s[6], s[7]);
  se[2] = make_float4(s[8], s[9], s[10], s[11]);
  se[3] = make_float4(s[12], s[13], s[14], s[15]);
  sp[0] = make_float4(P[0], P[1], P[2], P[3]);
  sp[1] = make_float4(P[4], P[5], P[6], P[7]);
  sp[2] = make_float4(P[8], P[9], P[10], P[11]);
  sp[3] = make_float4(P[12], P[13], P[14], P[15]);
}

// In-place: sEnd[o] is replaced by the chunk's INITIAL state.
__global__ __launch_bounds__(256) void scan_passB(
    float* __restrict__ sEnd, const float* __restrict__ sProd) {
  int g = blockIdx.x * 256 + threadIdx.x;  // 65,536
  int n = g & 15;
  int e = (g >> 4) & (DI - 1);
  int b = g >> 15;
  float s = 0.f;
  for (int c = 0; c < NC; ++c) {
    size_t o = (((size_t)b * NC + c) * DI + e) * DSTATE + n;
    float se = sEnd[o];
    float sp = sProd[o];
    sEnd[o] = s;
    s = fmaf(s, sp, se);
  }
}

__global__ __launch_bounds__(256) void scan_passC(
    const unsigned short* __restrict__ dB, const unsigned short* __restrict__ u,
    const unsigned short* __restrict__ z, const float* __restrict__ bc,
    const float* __restrict__ A_log, const float* __restrict__ Dv,
    const float* __restrict__ sInit, unsigned short* __restrict__ gOut) {
  int g = blockIdx.x * 256 + threadIdx.x;  // 262144
  int e = g & (DI - 1);
  int c = (g >> 11) & (NC - 1);
  int b = g >> 17;

  float nA[DSTATE];
#pragma unroll
  for (int n = 0; n < DSTATE; ++n) nA[n] = -__expf(A_log[e * DSTATE + n]);
  const float nA0 = nA[0];
  bool aok = true;
#pragma unroll
  for (int n = 1; n < DSTATE; ++n)
    aok = aok && (fabsf(nA[n] - (float)(n + 1) * nA0) <=
                  1e-4f * fabsf(nA[n]));
  const float Dval = Dv[e];

  size_t off = ((size_t)b * LSEQ + c * TC) * DI + e;
  size_t boff = ((size_t)b * LSEQ + c * TC) * 32;

  float s[DSTATE];
  {
    size_t o = (((size_t)b * NC + c) * DI + e) * DSTATE;
    const float4* si = reinterpret_cast<const float4*>(&sInit[o]);
    float4 s0 = si[0], s1 = si[1], s2 = si[2], s3 = si[3];
    s[0] = s0.x; s[1] = s0.y; s[2] = s0.z; s[3] = s0.w;
    s[4] = s1.x; s[5] = s1.y; s[6] = s1.z; s[7] = s1.w;
    s[8] = s2.x; s[9] = s2.y; s[10] = s2.z; s[11] = s2.w;
    s[12] = s3.x; s[13] = s3.y; s[14] = s3.z; s[15] = s3.w;
  }

  float d = bf2f(dB[off]);
  float ut = bf2f(u[off]);
  float zt = bf2f(z[off]);
  float4 B0 = *reinterpret_cast<const float4*>(&bc[boff]);
  float4 B1 = *reinterpret_cast<const float4*>(&bc[boff + 4]);
  float4 B2 = *reinterpret_cast<const float4*>(&bc[boff + 8]);
  float4 B3 = *reinterpret_cast<const float4*>(&bc[boff + 12]);
  float4 C0 = *reinterpret_cast<const float4*>(&bc[boff + 16]);
  float4 C1 = *reinterpret_cast<const float4*>(&bc[boff + 20]);
  float4 C2 = *reinterpret_cast<const float4*>(&bc[boff + 24]);
  float4 C3 = *reinterpret_cast<const float4*>(&bc[boff + 28]);

  for (int t = 0; t < TC; ++t) {
    float d_n = 0.f, ut_n = 0.f, zt_n = 0.f;
    float4 B0n = {}, B1n = {}, B2n = {}, B3n = {};
    float4 C0n = {}, C1n = {}, C2n = {}, C3n = {};
    if (t + 1 < TC) {
      d_n = bf2f(dB[off + DI]);
      ut_n = bf2f(u[off + DI]);
      zt_n = bf2f(z[off + DI]);
      B0n = *reinterpret_cast<const float4*>(&bc[boff + 32]);
      B1n = *reinterpret_cast<const float4*>(&bc[boff + 36]);
      B2n = *reinterpret_cast<const float4*>(&bc[boff + 40]);
      B3n = *reinterpret_cast<const float4*>(&bc[boff + 44]);
      C0n = *reinterpret_cast<const float4*>(&bc[boff + 48]);
      C1n = *reinterpret_cast<const float4*>(&bc[boff + 52]);
      C2n = *reinterpret_cast<const float4*>(&bc[boff + 56]);
      C3n = *reinterpret_cast<const float4*>(&bc[boff + 60]);
    }

    float db = d * ut;
    float dA[DSTATE];
    if (aok) {
      float qq = __expf(d * nA0);
      dA[0] = qq;
#pragma unroll
      for (int n = 1; n < DSTATE; ++n) dA[n] = dA[n - 1] * qq;
    } else {
#pragma unroll
      for (int n = 0; n < DSTATE; ++n) dA[n] = __expf(d * nA[n]);
    }
    float Bv[DSTATE] = {B0.x, B0.y, B0.z, B0.w, B1.x, B1.y, B1.z, B1.w,
                        B2.x, B2.y, B2.z, B2.w, B3.x, B3.y, B3.z, B3.w};
    float Cv[DSTATE] = {C0.x, C0.y, C0.z, C0.w, C1.x, C1.y, C1.z, C1.w,
                        C2.x, C2.y, C2.z, C2.w, C3.x, C3.y, C3.z, C3.w};
    float y = 0.f;
#pragma unroll
    for (int n = 0; n < DSTATE; ++n) {
      s[n] = fmaf(s[n], dA[n], db * Bv[n]);
      y = fmaf(s[n], Cv[n], y);
    }
    float gate = zt / (1.f + __expf(-zt));
    gOut[off] = f2bf((y + Dval * ut) * gate);

    off += DI;
    boff += 32;
    d = d_n; ut = ut_n; zt = zt_n;
    B0 = B0n; B1 = B1n; B2 = B2n; B3 = B3n;
    C0 = C0n; C1 = C1n; C2 = C2n; C3 = C3n;
  }
}

// ---------------------------------------------------------------------------
extern "C" void kernel_launch(void* const* d_in, const int* in_sizes, int n_in,
                              void* d_out, int out_size, void* d_ws,
                              size_t ws_size, hipStream_t stream) {
  const float* hs = (const float*)d_in[0];
  const float* in2 = (const float*)d_in[1];
  const float* w1 = (const float*)d_in[2];
  const float* w2 = (const float*)d_in[3];
  const float* cw = (const float*)d_in[4];
  const float* cb = (const float*)d_in[5];
  const float* xpw = (const float*)d_in[6];
  const float* dtw = (const float*)d_in[7];
  const float* dtb = (const float*)d_in[8];
  const float* alog = (const float*)d_in[9];
  const float* Dv = (const float*)d_in[10];
  const float* ow = (const float*)d_in[11];
  float* out = (float*)d_out;

  const size_t BLE = (size_t)BATCH * LSEQ * DI;   // 8,388,608
  const size_t BLM = (size_t)BATCH * LSEQ * DM;   // 4,194,304
  const size_t WN = (size_t)DI * DM;              // 2,097,152
  const size_t SC = (size_t)BATCH * NC * DI * DSTATE;  // 4,194,304

  // Regions (floats):
  float* W = (float*)d_ws;
  float* bufX = W;             // BLE: x_pre f32; later dB (bf16, half region)
  float* M2 = W + BLE;         // BLE/2: hsb -> zb (bf16)
  float* M3 = M2 + BLE / 2;    // BLE/2: in2b -> ub (bf16)
  float* M4 = M3 + BLE / 2;    // BLE/2: wb1|wb2 -> xdblP|xpwB|dtB|dtwB -> bufG
  float* sEnd = M4 + BLE / 2;  // SC (holds sInit after passB)
  float* sProd = sEnd + SC;    // SC (dead after passB; owb here)
  float* BC = sProd + SC;      // 4096*32 = 131,072
  // total = 8.39M + 3*4.19M + 2*4.19M + 0.13M floats = ~29.5M f = 118 MB

  unsigned short* hsb = (unsigned short*)M2;
  unsigned short* zb = (unsigned short*)M2;
  unsigned short* in2b = (unsigned short*)M3;
  unsigned short* ub = (unsigned short*)M3;
  unsigned short* wb1 = (unsigned short*)M4;
  unsigned short* wb2 = wb1 + WN;
  float* xdblP = M4;                                        // 4*PN floats
  unsigned short* xpwB = (unsigned short*)(M4 + 4 * PN);    // 96*2048
  unsigned short* dtB = (unsigned short*)(M4 + 4 * PN + 98304 + 16);
  unsigned short* dtwB = (unsigned short*)(M4 + 4 * PN + 98304 + 131072 + 32);
  unsigned short* bufG = (unsigned short*)M4;
  unsigned short* dB = (unsigned short*)bufX;
  unsigned short* owb = (unsigned short*)sProd;

  const int M = BATCH * LSEQ;  // 4096
  dim3 blk(256);

  // 0. convert GEMM operands to bf16
  cvt_bf16_kernel<<<(int)(BLM / 8 / 256), blk, 0, stream>>>(hs, hsb,
                                                            (int)(BLM / 8));
  cvt_bf16_kernel<<<(int)(BLM / 8 / 256), blk, 0, stream>>>(in2, in2b,
                                                            (int)(BLM / 8));
  cvt_bf16_kernel<<<(int)(WN / 8 / 256), blk, 0, stream>>>(w1, wb1,
                                                           (int)(WN / 8));
  cvt_bf16_kernel<<<(int)(WN / 8 / 256), blk, 0, stream>>>(w2, wb2,
                                                           (int)(WN / 8));
  // 1. x_pre = hs @ w1^T  (f32 out)
  gemm_bf16_t<float><<<dim3(DI / 128, M / 128), blk, 0, stream>>>(
      hsb, wb1, bufX, DM, DM, DM, DI);
  // 2. z = in2 @ w2^T  (bf16 out; hsb dead)
  gemm_bf16_t<unsigned short><<<dim3(DI / 128, M / 128), blk, 0, stream>>>(
      in2b, wb2, zb, DM, DM, DM, DI);
  // 3. u = silu(conv(x_pre) + cb)  (bf16 out; in2b dead)
  conv_silu_kernel<<<(M * (DI / 4)) / 256, blk, 0, stream>>>(bufX, cw, cb, ub);
  // 3b. convert xpw, dtw (wb1/wb2 dead)
  cvt_bf16_kernel<<<96, blk, 0, stream>>>(xpw, xpwB, XDR * DI / 8);
  cvt_bf16_kernel<<<64, blk, 0, stream>>>(dtw, dtwB, DI * DTR / 8);
  // 4. x_dbl partials = u @ xpw^T (split-K x4, MFMA) + reduce
  gemm_xdbl<<<dim3(M / 128, 4), blk, 0, stream>>>(ub, xpwB, xdblP);
  reduce4x_kernel<<<(M * XDR) / 256, blk, 0, stream>>>(xdblP, dtB, BC);
  // 5. d = softplus(dt @ dtw^T + dtb)  (bf16 out into bufX region; x_pre dead)
  gemm_delta<<<dim3(DI / 128, M / 128), blk, 0, stream>>>(
      dtB, dtwB, dtb, dB, DTR, DTR, DTR, DI);
  // 6. chunked scan; passB in-place (sEnd -> sInit); passC emits g bf16
  scan_passA<<<(BATCH * DI * NC) / 256, blk, 0, stream>>>(dB, ub, BC, alog,
                                                          sEnd, sProd);
  scan_passB<<<(BATCH * DI * DSTATE) / 256, blk, 0, stream>>>(sEnd, sProd);
  cvt_bf16_kernel<<<(int)(WN / 8 / 256), blk, 0, stream>>>(ow, owb,
                                                           (int)(WN / 8));
  scan_passC<<<(BATCH * DI * NC) / 256, blk, 0, stream>>>(
      dB, ub, zb, BC, alog, Dv, sEnd, bufG);
  // 7. out = g @ ow^T
  gemm_bf16_t<float><<<dim3(DM / 128, M / 128), blk, 0, stream>>>(
      bufG, owb, out, DI, DI, DI, DM);
}

// Round 13
// 247.032 us; speedup vs baseline: 6.6304x; 1.0094x over previous
//
#include <hip/hip_runtime.h>
#include <cstddef>
#include <cmath>
#include <type_traits>

#define BATCH 2
#define LSEQ 2048
#define DM 1024
#define DSTATE 16
#define DI 2048
#define DTR 64
#define XDR 96   // DTR + 2*DSTATE
#define NC 64    // scan chunks
#define TC 32    // timesteps per chunk (NC*TC == LSEQ)
#define PN (4096 * 96)  // per-z x_dbl partial size

using f32x4 = __attribute__((ext_vector_type(4))) float;
using bf16x8 = __attribute__((ext_vector_type(8))) short;

__device__ __forceinline__ unsigned short f2bf(float f) {
  union { float f; unsigned int u; } c; c.f = f;
  unsigned int u = c.u;
  return (unsigned short)((u + 0x7FFFu + ((u >> 16) & 1u)) >> 16);  // RNE
}
__device__ __forceinline__ float bf2f(unsigned short h) {
  union { unsigned int u; float f; } c; c.u = ((unsigned int)h) << 16;
  return c.f;
}
__device__ __forceinline__ unsigned int pack2(float a, float b) {
  return (unsigned int)f2bf(a) | ((unsigned int)f2bf(b) << 16);
}

__device__ __forceinline__ void gl_lds16(const void* g, void* l) {
  __builtin_amdgcn_global_load_lds(
      (const __attribute__((address_space(1))) void*)g,
      (__attribute__((address_space(3))) void*)l, 16, 0, 0);
}

__device__ __forceinline__ float softplus_fast(float x) {
  float ex = __expf(x);
  return (x > 20.f) ? x : __logf(1.f + ex);
}

// dA[n] = q^(n+1), binary-power tree (depth ~4 instead of 15-serial).
__device__ __forceinline__ void pow_tree(float q1, float* dA) {
  float q2 = q1 * q1;
  float q3 = q2 * q1;
  float q4 = q2 * q2;
  float q8 = q4 * q4;
  float q5 = q4 * q1, q6 = q4 * q2, q7 = q4 * q3;
  dA[0] = q1;  dA[1] = q2;  dA[2] = q3;  dA[3] = q4;
  dA[4] = q5;  dA[5] = q6;  dA[6] = q7;  dA[7] = q8;
  dA[8] = q8 * q1;  dA[9] = q8 * q2;  dA[10] = q8 * q3;  dA[11] = q8 * q4;
  dA[12] = q8 * q5; dA[13] = q8 * q6; dA[14] = q8 * q7;  dA[15] = q8 * q8;
}

// ---------------------------------------------------------------------------
// f32 -> bf16 conversion, 8 elems/thread (exact-size grids).
// ---------------------------------------------------------------------------
__global__ __launch_bounds__(256) void cvt_bf16_kernel(
    const float* __restrict__ s, unsigned short* __restrict__ d, int n8) {
  int i = blockIdx.x * 256 + threadIdx.x;
  if (i >= n8) return;
  const float4* sp = reinterpret_cast<const float4*>(s) + (size_t)i * 2;
  float4 a = sp[0], b = sp[1];
  uint4 v = make_uint4(pack2(a.x, a.y), pack2(a.z, a.w), pack2(b.x, b.y),
                       pack2(b.z, b.w));
  *(reinterpret_cast<uint4*>(d) + i) = v;
}

// ---------------------------------------------------------------------------
// NT GEMM, bf16 in, f32 or bf16 out: C[m,n] = sum_k A[m*lda+k]*B[n*ldb+k].
// BM=BN=128, BK=64, 4 waves (2x2), 64x64/wave.  global_load_lds staging with
// pre-swizzled source slots (slot ^= row&7) + matching XOR on ds_read.
// XCD-aware bijective block swizzle (requires nwg % 8 == 0).
// ---------------------------------------------------------------------------
template <typename OutT>
__global__ __launch_bounds__(256) void gemm_bf16_t(
    const unsigned short* __restrict__ A, const unsigned short* __restrict__ B,
    OutT* __restrict__ C, int K, int lda, int ldb, int ldc) {
  __shared__ __align__(16) unsigned short As[128][64];
  __shared__ __align__(16) unsigned short Bs[128][64];

  const int tid = threadIdx.x;
  const int lane = tid & 63;
  const int w = tid >> 6;

  const int gx = gridDim.x;
  const int nwg = gx * gridDim.y;
  const int id = blockIdx.y * gx + blockIdx.x;
  const int cpx = nwg >> 3;
  const int lt = (id & 7) * cpx + (id >> 3);
  const size_t m0 = (size_t)(lt / gx) * 128;
  const size_t n0 = (size_t)(lt % gx) * 128;

  const int rsub = lane >> 3;
  const int sslot = (lane & 7) ^ rsub;
  const unsigned short* Ab = A + m0 * lda + (size_t)rsub * lda + sslot * 8;
  const unsigned short* Bb = B + n0 * ldb + (size_t)rsub * ldb + sslot * 8;

  f32x4 acc[4][4] = {};

  const int fr = lane & 15;
  const int q = lane >> 4;
  const int f7 = fr & 7;

  for (int k0 = 0; k0 < K; k0 += 64) {
#pragma unroll
    for (int i = 0; i < 4; ++i) {
      const int r0 = w * 32 + i * 8;
      gl_lds16(Ab + (size_t)r0 * lda + k0, &As[r0][0]);
      gl_lds16(Bb + (size_t)r0 * ldb + k0, &Bs[r0][0]);
    }
    __syncthreads();

    bf16x8 af[4][2], bf_[4][2];
#pragma unroll
    for (int i = 0; i < 4; ++i) {
#pragma unroll
      for (int kk = 0; kk < 2; ++kk) {
        const int sA = (((kk * 4 + q) ^ f7) << 3);
        af[i][kk] = *reinterpret_cast<const bf16x8*>(
            &As[(w >> 1) * 64 + i * 16 + fr][sA]);
        bf_[i][kk] = *reinterpret_cast<const bf16x8*>(
            &Bs[(w & 1) * 64 + i * 16 + fr][sA]);
      }
    }
#pragma unroll
    for (int kk = 0; kk < 2; ++kk)
#pragma unroll
      for (int i = 0; i < 4; ++i)
#pragma unroll
        for (int j = 0; j < 4; ++j)
          acc[i][j] = __builtin_amdgcn_mfma_f32_16x16x32_bf16(
              af[i][kk], bf_[j][kk], acc[i][j], 0, 0, 0);
    __syncthreads();
  }

  const int crb = q * 4;
#pragma unroll
  for (int i = 0; i < 4; ++i) {
    size_t row = m0 + (w >> 1) * 64 + i * 16 + crb;
#pragma unroll
    for (int j = 0; j < 4; ++j) {
      size_t col = n0 + (w & 1) * 64 + j * 16 + fr;
#pragma unroll
      for (int r = 0; r < 4; ++r) {
        if constexpr (std::is_same_v<OutT, unsigned short>)
          C[(row + r) * ldc + col] = f2bf(acc[i][j][r]);
        else
          C[(row + r) * ldc + col] = acc[i][j][r];
      }
    }
  }
}

// ---------------------------------------------------------------------------
// Delta GEMM with fused bias+softplus epilogue, bf16 out.
// ---------------------------------------------------------------------------
__global__ __launch_bounds__(256) void gemm_delta(
    const unsigned short* __restrict__ A, const unsigned short* __restrict__ B,
    const float* __restrict__ bias, unsigned short* __restrict__ C, int K,
    int lda, int ldb, int ldc) {
  __shared__ __align__(16) unsigned short As[128][64];
  __shared__ __align__(16) unsigned short Bs[128][64];

  const int tid = threadIdx.x;
  const int lane = tid & 63;
  const int w = tid >> 6;

  const int gx = gridDim.x;
  const int nwg = gx * gridDim.y;
  const int id = blockIdx.y * gx + blockIdx.x;
  const int cpx = nwg >> 3;
  const int lt = (id & 7) * cpx + (id >> 3);
  const size_t m0 = (size_t)(lt / gx) * 128;
  const size_t n0 = (size_t)(lt % gx) * 128;

  const int rsub = lane >> 3;
  const int sslot = (lane & 7) ^ rsub;
  const unsigned short* Ab = A + m0 * lda + (size_t)rsub * lda + sslot * 8;
  const unsigned short* Bb = B + n0 * ldb + (size_t)rsub * ldb + sslot * 8;

  f32x4 acc[4][4] = {};

  const int fr = lane & 15;
  const int q = lane >> 4;
  const int f7 = fr & 7;

  for (int k0 = 0; k0 < K; k0 += 64) {
#pragma unroll
    for (int i = 0; i < 4; ++i) {
      const int r0 = w * 32 + i * 8;
      gl_lds16(Ab + (size_t)r0 * lda + k0, &As[r0][0]);
      gl_lds16(Bb + (size_t)r0 * ldb + k0, &Bs[r0][0]);
    }
    __syncthreads();

    bf16x8 af[4][2], bf_[4][2];
#pragma unroll
    for (int i = 0; i < 4; ++i) {
#pragma unroll
      for (int kk = 0; kk < 2; ++kk) {
        const int sA = (((kk * 4 + q) ^ f7) << 3);
        af[i][kk] = *reinterpret_cast<const bf16x8*>(
            &As[(w >> 1) * 64 + i * 16 + fr][sA]);
        bf_[i][kk] = *reinterpret_cast<const bf16x8*>(
            &Bs[(w & 1) * 64 + i * 16 + fr][sA]);
      }
    }
#pragma unroll
    for (int kk = 0; kk < 2; ++kk)
#pragma unroll
      for (int i = 0; i < 4; ++i)
#pragma unroll
        for (int j = 0; j < 4; ++j)
          acc[i][j] = __builtin_amdgcn_mfma_f32_16x16x32_bf16(
              af[i][kk], bf_[j][kk], acc[i][j], 0, 0, 0);
    __syncthreads();
  }

  const int crb = q * 4;
#pragma unroll
  for (int i = 0; i < 4; ++i) {
    size_t row = m0 + (w >> 1) * 64 + i * 16 + crb;
#pragma unroll
    for (int j = 0; j < 4; ++j) {
      size_t col = n0 + (w & 1) * 64 + j * 16 + fr;
      float bv = bias[col];
#pragma unroll
      for (int r = 0; r < 4; ++r)
        C[(row + r) * ldc + col] = f2bf(softplus_fast(acc[i][j][r] + bv));
    }
  }
}

// ---------------------------------------------------------------------------
// Skinny x_dbl GEMM: P[z][m][c] = sum_{k in z-chunk} u[m][k]*xpw[c][k].
// ---------------------------------------------------------------------------
__global__ __launch_bounds__(256) void gemm_xdbl(
    const unsigned short* __restrict__ A,  // u bf16 [4096][2048]
    const unsigned short* __restrict__ B,  // xpw bf16 [96][2048]
    float* __restrict__ P) {               // partials [4][4096][96]
  __shared__ __align__(16) unsigned short As[128][64];
  __shared__ __align__(16) unsigned short Bs[96][64];

  const int tid = threadIdx.x;
  const int lane = tid & 63;
  const int w = tid >> 6;
  const size_t m0 = (size_t)blockIdx.x * 128;
  const int k0base = blockIdx.y * 512;

  const int rsub = lane >> 3;
  const int sslot = (lane & 7) ^ rsub;
  const unsigned short* Ab = A + m0 * DI + (size_t)rsub * DI + sslot * 8;
  const unsigned short* Bb = B + (size_t)rsub * DI + sslot * 8;

  f32x4 acc[4][3] = {};

  const int fr = lane & 15;
  const int q = lane >> 4;
  const int f7 = fr & 7;

  for (int ks = 0; ks < 8; ++ks) {
    const int k0 = k0base + ks * 64;
#pragma unroll
    for (int i = 0; i < 4; ++i) {
      const int r0 = w * 32 + i * 8;
      gl_lds16(Ab + (size_t)r0 * DI + k0, &As[r0][0]);
    }
#pragma unroll
    for (int i = 0; i < 3; ++i) {
      const int r0 = w * 24 + i * 8;
      gl_lds16(Bb + (size_t)r0 * DI + k0, &Bs[r0][0]);
    }
    __syncthreads();

    bf16x8 af[4][2], bf_[3][2];
#pragma unroll
    for (int kk = 0; kk < 2; ++kk) {
      const int sA = (((kk * 4 + q) ^ f7) << 3);
#pragma unroll
      for (int i = 0; i < 4; ++i)
        af[i][kk] = *reinterpret_cast<const bf16x8*>(
            &As[(w >> 1) * 64 + i * 16 + fr][sA]);
#pragma unroll
      for (int j = 0; j < 3; ++j)
        bf_[j][kk] = *reinterpret_cast<const bf16x8*>(
            &Bs[(w & 1) * 48 + j * 16 + fr][sA]);
    }
#pragma unroll
    for (int kk = 0; kk < 2; ++kk)
#pragma unroll
      for (int i = 0; i < 4; ++i)
#pragma unroll
        for (int j = 0; j < 3; ++j)
          acc[i][j] = __builtin_amdgcn_mfma_f32_16x16x32_bf16(
              af[i][kk], bf_[j][kk], acc[i][j], 0, 0, 0);
    __syncthreads();
  }

  float* Pz = P + (size_t)blockIdx.y * PN;
  const int crb = q * 4;
#pragma unroll
  for (int i = 0; i < 4; ++i) {
    size_t row = m0 + (w >> 1) * 64 + i * 16 + crb;
#pragma unroll
    for (int j = 0; j < 3; ++j) {
      int col = (w & 1) * 48 + j * 16 + fr;
#pragma unroll
      for (int r = 0; r < 4; ++r) Pz[(row + r) * XDR + col] = acc[i][j][r];
    }
  }
}

// reduce split-K partials; emit dt as bf16 (cols 0..63) and compact B/C f32.
__global__ __launch_bounds__(256) void reduce4x_kernel(
    const float* __restrict__ P, unsigned short* __restrict__ dtB,
    float* __restrict__ BC) {
  int i = blockIdx.x * 256 + threadIdx.x;  // < 4096*96
  int row = i / XDR, col = i - row * XDR;
  float s = (P[i] + P[PN + i]) + (P[2 * PN + i] + P[3 * PN + i]);
  if (col < 64)
    dtB[row * 64 + col] = f2bf(s);
  else
    BC[row * 32 + (col - 64)] = s;
}

// ---------------------------------------------------------------------------
// Depthwise causal conv (D_CONV=4) + bias + SiLU; f32 in, bf16 out.
// ---------------------------------------------------------------------------
__global__ __launch_bounds__(256) void conv_silu_kernel(
    const float* __restrict__ x, const float* __restrict__ w,
    const float* __restrict__ cb, unsigned short* __restrict__ out) {
  int idx = blockIdx.x * 256 + threadIdx.x;
  int e4 = idx % (DI / 4);
  int bl = idx / (DI / 4);
  int l = bl % LSEQ;
  int e = e4 * 4;

  const float4* cw = reinterpret_cast<const float4*>(w);
  float4 w0 = cw[e], w1 = cw[e + 1], w2 = cw[e + 2], w3 = cw[e + 3];
  float4 acc = *reinterpret_cast<const float4*>(&cb[e]);

#define TAPK(K, COMP)                                                       \
  {                                                                         \
    int ls = l - 3 + (K);                                                   \
    if (ls >= 0) {                                                          \
      float4 xv = *reinterpret_cast<const float4*>(                         \
          &x[((size_t)(bl) - 3 + (K)) * DI + e]);                           \
      acc.x = fmaf(xv.x, w0.COMP, acc.x);                                   \
      acc.y = fmaf(xv.y, w1.COMP, acc.y);                                   \
      acc.z = fmaf(xv.z, w2.COMP, acc.z);                                   \
      acc.w = fmaf(xv.w, w3.COMP, acc.w);                                   \
    }                                                                       \
  }
  TAPK(0, x)
  TAPK(1, y)
  TAPK(2, z)
  TAPK(3, w)
#undef TAPK

  acc.x = acc.x / (1.f + expf(-acc.x));
  acc.y = acc.y / (1.f + expf(-acc.y));
  acc.z = acc.z / (1.f + expf(-acc.z));
  acc.w = acc.w / (1.f + expf(-acc.w));
  *reinterpret_cast<uint2*>(&out[(size_t)bl * DI + e]) =
      make_uint2(pack2(acc.x, acc.y), pack2(acc.z, acc.w));
}

// ---------------------------------------------------------------------------
// Chunked selective scan, 16 states/thread.  d (pre-softplus'ed) bf16;
// u,z bf16; B/C read per-step from the compact [BL][32] f32 buffer
// (wave-uniform broadcast, L1/L2-resident -> no prefetch registers).
// dA computed via one exp + binary-power tree when A_log matches the
// model's arange pattern (uniform runtime check, generic fallback).
// ---------------------------------------------------------------------------
__global__ __launch_bounds__(256) void scan_passA(
    const unsigned short* __restrict__ dB, const unsigned short* __restrict__ u,
    const float* __restrict__ bc, const float* __restrict__ A_log,
    float* __restrict__ sEnd, float* __restrict__ sProd) {
  int g = blockIdx.x * 256 + threadIdx.x;  // B*E*NC = 262144
  int e = g & (DI - 1);
  int c = (g >> 11) & (NC - 1);
  int b = g >> 17;

  const float nA0 = -__expf(A_log[e * DSTATE]);
  bool aok = true;
#pragma unroll
  for (int n = 1; n < DSTATE; ++n) {
    float nAn = -__expf(A_log[e * DSTATE + n]);
    aok = aok && (fabsf(nAn - (float)(n + 1) * nA0) <= 1e-4f * fabsf(nAn));
  }

  size_t off = ((size_t)b * LSEQ + c * TC) * DI + e;
  size_t boff = ((size_t)b * LSEQ + c * TC) * 32;

  float s[DSTATE], P[DSTATE];
#pragma unroll
  for (int n = 0; n < DSTATE; ++n) { s[n] = 0.f; P[n] = 1.f; }

  float d = bf2f(dB[off]);
  float ut = bf2f(u[off]);

  for (int t = 0; t < TC; ++t) {
    float d_n = 0.f, ut_n = 0.f;
    if (t + 1 < TC) {
      d_n = bf2f(dB[off + DI]);
      ut_n = bf2f(u[off + DI]);
    }

    float db = d * ut;
    float dA[DSTATE];
    if (aok) {
      pow_tree(__expf(d * nA0), dA);
    } else {
#pragma unroll
      for (int n = 0; n < DSTATE; ++n)
        dA[n] = __expf(-d * __expf(A_log[e * DSTATE + n]));
    }
    const float4* bcp = reinterpret_cast<const float4*>(&bc[boff]);
    float4 B0 = bcp[0], B1 = bcp[1], B2 = bcp[2], B3 = bcp[3];
    float Bv[DSTATE] = {B0.x, B0.y, B0.z, B0.w, B1.x, B1.y, B1.z, B1.w,
                        B2.x, B2.y, B2.z, B2.w, B3.x, B3.y, B3.z, B3.w};
#pragma unroll
    for (int n = 0; n < DSTATE; ++n) {
      s[n] = fmaf(s[n], dA[n], db * Bv[n]);
      P[n] *= dA[n];
    }
    off += DI;
    boff += 32;
    d = d_n; ut = ut_n;
  }

  size_t o = (((size_t)b * NC + c) * DI + e) * DSTATE;
  float4* se = reinterpret_cast<float4*>(&sEnd[o]);
  float4* sp = reinterpret_cast<float4*>(&sProd[o]);
  se[0] = make_float4(s[0], s[1], s[2], s[3]);
  se[1] = make_float4(s[4], s[5], s[6], s[7]);
  se[2] = make_float4(s[8], s[9], s[10], s[11]);
  se[3] = make_float4(s[12], s[13], s[14], s[15]);
  sp[0] = make_float4(P[0], P[1], P[2], P[3]);
  sp[1] = make_float4(P[4], P[5], P[6], P[7]);
  sp[2] = make_float4(P[8], P[9], P[10], P[11]);
  sp[3] = make_float4(P[12], P[13], P[14], P[15]);
}

// In-place: sEnd[o] is replaced by the chunk's INITIAL state.
__global__ __launch_bounds__(256) void scan_passB(
    float* __restrict__ sEnd, const float* __restrict__ sProd) {
  int g = blockIdx.x * 256 + threadIdx.x;  // 65,536
  int n = g & 15;
  int e = (g >> 4) & (DI - 1);
  int b = g >> 15;
  float s = 0.f;
  for (int c = 0; c < NC; ++c) {
    size_t o = (((size_t)b * NC + c) * DI + e) * DSTATE + n;
    float se = sEnd[o];
    float sp = sProd[o];
    sEnd[o] = s;
    s = fmaf(s, sp, se);
  }
}

__global__ __launch_bounds__(256) void scan_passC(
    const unsigned short* __restrict__ dB, const unsigned short* __restrict__ u,
    const unsigned short* __restrict__ z, const float* __restrict__ bc,
    const float* __restrict__ A_log, const float* __restrict__ Dv,
    const float* __restrict__ sInit, unsigned short* __restrict__ gOut) {
  int g = blockIdx.x * 256 + threadIdx.x;  // 262144
  int e = g & (DI - 1);
  int c = (g >> 11) & (NC - 1);
  int b = g >> 17;

  const float nA0 = -__expf(A_log[e * DSTATE]);
  bool aok = true;
#pragma unroll
  for (int n = 1; n < DSTATE; ++n) {
    float nAn = -__expf(A_log[e * DSTATE + n]);
    aok = aok && (fabsf(nAn - (float)(n + 1) * nA0) <= 1e-4f * fabsf(nAn));
  }
  const float Dval = Dv[e];

  size_t off = ((size_t)b * LSEQ + c * TC) * DI + e;
  size_t boff = ((size_t)b * LSEQ + c * TC) * 32;

  float s[DSTATE];
  {
    size_t o = (((size_t)b * NC + c) * DI + e) * DSTATE;
    const float4* si = reinterpret_cast<const float4*>(&sInit[o]);
    float4 s0 = si[0], s1 = si[1], s2 = si[2], s3 = si[3];
    s[0] = s0.x; s[1] = s0.y; s[2] = s0.z; s[3] = s0.w;
    s[4] = s1.x; s[5] = s1.y; s[6] = s1.z; s[7] = s1.w;
    s[8] = s2.x; s[9] = s2.y; s[10] = s2.z; s[11] = s2.w;
    s[12] = s3.x; s[13] = s3.y; s[14] = s3.z; s[15] = s3.w;
  }

  float d = bf2f(dB[off]);
  float ut = bf2f(u[off]);
  float zt = bf2f(z[off]);

  for (int t = 0; t < TC; ++t) {
    float d_n = 0.f, ut_n = 0.f, zt_n = 0.f;
    if (t + 1 < TC) {
      d_n = bf2f(dB[off + DI]);
      ut_n = bf2f(u[off + DI]);
      zt_n = bf2f(z[off + DI]);
    }

    float db = d * ut;
    float dA[DSTATE];
    if (aok) {
      pow_tree(__expf(d * nA0), dA);
    } else {
#pragma unroll
      for (int n = 0; n < DSTATE; ++n)
        dA[n] = __expf(-d * __expf(A_log[e * DSTATE + n]));
    }
    const float4* bcp = reinterpret_cast<const float4*>(&bc[boff]);
    float4 B0 = bcp[0], B1 = bcp[1], B2 = bcp[2], B3 = bcp[3];
    float4 C0 = bcp[4], C1 = bcp[5], C2 = bcp[6], C3 = bcp[7];
    float Bv[DSTATE] = {B0.x, B0.y, B0.z, B0.w, B1.x, B1.y, B1.z, B1.w,
                        B2.x, B2.y, B2.z, B2.w, B3.x, B3.y, B3.z, B3.w};
    float Cv[DSTATE] = {C0.x, C0.y, C0.z, C0.w, C1.x, C1.y, C1.z, C1.w,
                        C2.x, C2.y, C2.z, C2.w, C3.x, C3.y, C3.z, C3.w};
    // 4-way parallel y accumulation (depth 4 + 2 instead of 16)
    float y0 = 0.f, y1 = 0.f, y2 = 0.f, y3 = 0.f;
#pragma unroll
    for (int n = 0; n < 4; ++n) {
      s[n] = fmaf(s[n], dA[n], db * Bv[n]);
      y0 = fmaf(s[n], Cv[n], y0);
      s[n + 4] = fmaf(s[n + 4], dA[n + 4], db * Bv[n + 4]);
      y1 = fmaf(s[n + 4], Cv[n + 4], y1);
      s[n + 8] = fmaf(s[n + 8], dA[n + 8], db * Bv[n + 8]);
      y2 = fmaf(s[n + 8], Cv[n + 8], y2);
      s[n + 12] = fmaf(s[n + 12], dA[n + 12], db * Bv[n + 12]);
      y3 = fmaf(s[n + 12], Cv[n + 12], y3);
    }
    float y = (y0 + y1) + (y2 + y3);
    float gate = zt / (1.f + __expf(-zt));
    gOut[off] = f2bf((y + Dval * ut) * gate);

    off += DI;
    boff += 32;
    d = d_n; ut = ut_n; zt = zt_n;
  }
}

// ---------------------------------------------------------------------------
extern "C" void kernel_launch(void* const* d_in, const int* in_sizes, int n_in,
                              void* d_out, int out_size, void* d_ws,
                              size_t ws_size, hipStream_t stream) {
  const float* hs = (const float*)d_in[0];
  const float* in2 = (const float*)d_in[1];
  const float* w1 = (const float*)d_in[2];
  const float* w2 = (const float*)d_in[3];
  const float* cw = (const float*)d_in[4];
  const float* cb = (const float*)d_in[5];
  const float* xpw = (const float*)d_in[6];
  const float* dtw = (const float*)d_in[7];
  const float* dtb = (const float*)d_in[8];
  const float* alog = (const float*)d_in[9];
  const float* Dv = (const float*)d_in[10];
  const float* ow = (const float*)d_in[11];
  float* out = (float*)d_out;

  const size_t BLE = (size_t)BATCH * LSEQ * DI;   // 8,388,608
  const size_t BLM = (size_t)BATCH * LSEQ * DM;   // 4,194,304
  const size_t WN = (size_t)DI * DM;              // 2,097,152
  const size_t SC = (size_t)BATCH * NC * DI * DSTATE;  // 4,194,304

  // Regions (floats):
  float* W = (float*)d_ws;
  float* bufX = W;             // BLE: x_pre f32; later dB (bf16, half region)
  float* M2 = W + BLE;         // BLE/2: hsb -> zb (bf16)
  float* M3 = M2 + BLE / 2;    // BLE/2: in2b -> ub (bf16)
  float* M4 = M3 + BLE / 2;    // BLE/2: wb1|wb2 -> xdblP|xpwB|dtB|dtwB -> bufG
  float* sEnd = M4 + BLE / 2;  // SC (holds sInit after passB)
  float* sProd = sEnd + SC;    // SC (dead after passB; owb here)
  float* BC = sProd + SC;      // 4096*32 = 131,072

  unsigned short* hsb = (unsigned short*)M2;
  unsigned short* zb = (unsigned short*)M2;
  unsigned short* in2b = (unsigned short*)M3;
  unsigned short* ub = (unsigned short*)M3;
  unsigned short* wb1 = (unsigned short*)M4;
  unsigned short* wb2 = wb1 + WN;
  float* xdblP = M4;                                        // 4*PN floats
  unsigned short* xpwB = (unsigned short*)(M4 + 4 * PN);    // 96*2048
  unsigned short* dtB = (unsigned short*)(M4 + 4 * PN + 98304 + 16);
  unsigned short* dtwB = (unsigned short*)(M4 + 4 * PN + 98304 + 131072 + 32);
  unsigned short* bufG = (unsigned short*)M4;
  unsigned short* dB = (unsigned short*)bufX;
  unsigned short* owb = (unsigned short*)sProd;

  const int M = BATCH * LSEQ;  // 4096
  dim3 blk(256);

  // 0. convert GEMM operands to bf16
  cvt_bf16_kernel<<<(int)(BLM / 8 / 256), blk, 0, stream>>>(hs, hsb,
                                                            (int)(BLM / 8));
  cvt_bf16_kernel<<<(int)(BLM / 8 / 256), blk, 0, stream>>>(in2, in2b,
                                                            (int)(BLM / 8));
  cvt_bf16_kernel<<<(int)(WN / 8 / 256), blk, 0, stream>>>(w1, wb1,
                                                           (int)(WN / 8));
  cvt_bf16_kernel<<<(int)(WN / 8 / 256), blk, 0, stream>>>(w2, wb2,
                                                           (int)(WN / 8));
  // 1. x_pre = hs @ w1^T  (f32 out)
  gemm_bf16_t<float><<<dim3(DI / 128, M / 128), blk, 0, stream>>>(
      hsb, wb1, bufX, DM, DM, DM, DI);
  // 2. z = in2 @ w2^T  (bf16 out; hsb dead)
  gemm_bf16_t<unsigned short><<<dim3(DI / 128, M / 128), blk, 0, stream>>>(
      in2b, wb2, zb, DM, DM, DM, DI);
  // 3. u = silu(conv(x_pre) + cb)  (bf16 out; in2b dead)
  conv_silu_kernel<<<(M * (DI / 4)) / 256, blk, 0, stream>>>(bufX, cw, cb, ub);
  // 3b. convert xpw, dtw (wb1/wb2 dead)
  cvt_bf16_kernel<<<96, blk, 0, stream>>>(xpw, xpwB, XDR * DI / 8);
  cvt_bf16_kernel<<<64, blk, 0, stream>>>(dtw, dtwB, DI * DTR / 8);
  // 4. x_dbl partials = u @ xpw^T (split-K x4, MFMA) + reduce
  gemm_xdbl<<<dim3(M / 128, 4), blk, 0, stream>>>(ub, xpwB, xdblP);
  reduce4x_kernel<<<(M * XDR) / 256, blk, 0, stream>>>(xdblP, dtB, BC);
  // 5. d = softplus(dt @ dtw^T + dtb)  (bf16 out into bufX region)
  gemm_delta<<<dim3(DI / 128, M / 128), blk, 0, stream>>>(
      dtB, dtwB, dtb, dB, DTR, DTR, DTR, DI);
  // 6. chunked scan; passB in-place (sEnd -> sInit); passC emits g bf16
  scan_passA<<<(BATCH * DI * NC) / 256, blk, 0, stream>>>(dB, ub, BC, alog,
                                                          sEnd, sProd);
  scan_passB<<<(BATCH * DI * DSTATE) / 256, blk, 0, stream>>>(sEnd, sProd);
  cvt_bf16_kernel<<<(int)(WN / 8 / 256), blk, 0, stream>>>(ow, owb,
                                                           (int)(WN / 8));
  scan_passC<<<(BATCH * DI * NC) / 256, blk, 0, stream>>>(
      dB, ub, zb, BC, alog, Dv, sEnd, bufG);
  // 7. out = g @ ow^T
  gemm_bf16_t<float><<<dim3(DM / 128, M / 128), blk, 0, stream>>>(
      bufG, owb, out, DI, DI, DI, DM);
}